// Round 6
// baseline (311.093 us; speedup 1.0000x reference)
//
#include <hip/hip_runtime.h>

#define IN_FEATS 256
#define HID 64
#define OUTF 32
#define JK (3*HID)

#define NB   256   // buckets (allocated); actual used = (N+511)>>9
#define BSH  9     // bucket covers 512 nodes
#define NBLK 512   // edge-chunk blocks for hist/scatter
// NOTE: packed pairbuf assumes N <= 2^17 (src fits 17 bits). N=100000 here.

typedef __attribute__((ext_vector_type(4))) float floatx4;
typedef __attribute__((ext_vector_type(8))) short shortx8;

// ---------------- bf16 helpers (RNE) ----------------
__device__ inline unsigned short f2bf(float f) {
    unsigned u = __float_as_uint(f);
    unsigned r = (u + 0x7fffu + ((u >> 16) & 1u)) >> 16;
    return (unsigned short)r;
}
__device__ inline float bf2f(unsigned short u) {
    return __uint_as_float(((unsigned)u) << 16);
}
__device__ inline unsigned pack2(float a, float b) {
    return (unsigned)f2bf(a) | ((unsigned)f2bf(b) << 16);
}

// ---------------- P1: per-block LDS histograms over dst-buckets and src-buckets ----
__global__ __launch_bounds__(256) void p1_hist(const int* __restrict__ src,
                                               const int* __restrict__ dst, int E,
                                               int* __restrict__ bhd, int* __restrict__ bhs) {
    __shared__ int hd[NB], hs[NB];
    int b = blockIdx.x;
    for (int t = threadIdx.x; t < NB; t += 256) { hd[t] = 0; hs[t] = 0; }
    __syncthreads();
    int cb = (E + NBLK - 1) / NBLK;
    int beg = b * cb, end = min(beg + cb, E);
    for (int e = beg + threadIdx.x; e < end; e += 256) {
        atomicAdd(&hd[dst[e] >> BSH], 1);
        atomicAdd(&hs[src[e] >> BSH], 1);
    }
    __syncthreads();
    for (int t = threadIdx.x; t < NB; t += 256) {
        bhd[b * NB + t] = hd[t];
        bhs[b * NB + t] = hs[t];
    }
}

// ---------------- P2a: per-(side,bucket) totals over block-histograms ----------------
__global__ __launch_bounds__(256) void p2a_tot(const int* __restrict__ bhd,
                                               const int* __restrict__ bhs,
                                               int* __restrict__ totd, int* __restrict__ tots,
                                               int nblk) {
    __shared__ int s[256];
    int side = blockIdx.x >> 8;     // grid = 512
    int t = blockIdx.x & 255;
    const int* bh = side ? bhs : bhd;
    int acc = 0;
    for (int k = threadIdx.x; k < nblk; k += 256) acc += bh[k * NB + t];
    s[threadIdx.x] = acc;
    __syncthreads();
    for (int off = 128; off > 0; off >>= 1) {
        if (threadIdx.x < off) s[threadIdx.x] += s[threadIdx.x + off];
        __syncthreads();
    }
    if (threadIdx.x == 0) (side ? tots : totd)[t] = s[0];
}

// ---------------- P2b: exclusive scan over bucket totals -> based/bases ----------------
__global__ __launch_bounds__(256) void p2b_scan(const int* __restrict__ totd,
                                                const int* __restrict__ tots,
                                                int* __restrict__ based, int* __restrict__ bases) {
    __shared__ int s[256];
    const int* tot = blockIdx.x ? tots : totd;
    int* bb = blockIdx.x ? bases : based;
    int t = threadIdx.x;
    int v = tot[t];
    s[t] = v;
    __syncthreads();
    for (int off = 1; off < 256; off <<= 1) {
        int u = (t >= off) ? s[t - off] : 0;
        __syncthreads();
        s[t] += u;
        __syncthreads();
    }
    bb[t] = s[t] - v;
    if (t == 255) bb[256] = s[255];
}

// ---------------- P2c: per-bucket prefix over blocks (in place) ----------------
__global__ __launch_bounds__(256) void p2c_off(int* __restrict__ bhd, int* __restrict__ bhs,
                                               const int* __restrict__ based,
                                               const int* __restrict__ bases, int nblk) {
    __shared__ int s[256];
    int side = blockIdx.x >> 8;     // grid = 512
    int t = blockIdx.x & 255;
    int* bh = side ? bhs : bhd;
    int carry = (side ? bases : based)[t];
    for (int k0 = 0; k0 < nblk; k0 += 256) {
        int k = k0 + threadIdx.x;
        int v = (k < nblk) ? bh[k * NB + t] : 0;
        s[threadIdx.x] = v;
        __syncthreads();
        for (int off = 1; off < 256; off <<= 1) {
            int u = (threadIdx.x >= off) ? s[threadIdx.x - off] : 0;
            __syncthreads();
            s[threadIdx.x] += u;
            __syncthreads();
        }
        if (k < nblk) bh[k * NB + t] = carry + s[threadIdx.x] - v;
        int tot = s[255];
        __syncthreads();
        carry += tot;
    }
}

// ---------------- P3: partition edges by bucket (LDS cursors, packed pairs) ----------
__global__ __launch_bounds__(256) void p3_scatter(const int* __restrict__ src,
                                                  const int* __restrict__ dst, int E,
                                                  const int* __restrict__ bhd,
                                                  const int* __restrict__ bhs,
                                                  int* __restrict__ pairbuf,
                                                  int* __restrict__ srctmp) {
    __shared__ int curd[NB], curs[NB];
    int b = blockIdx.x;
    for (int t = threadIdx.x; t < NB; t += 256) {
        curd[t] = bhd[b * NB + t];
        curs[t] = bhs[b * NB + t];
    }
    __syncthreads();
    int cb = (E + NBLK - 1) / NBLK;
    int beg = b * cb, end = min(beg + cb, E);
    for (int e = beg + threadIdx.x; e < end; e += 256) {
        int d = dst[e], sv = src[e];
        int pd = atomicAdd(&curd[d >> BSH], 1);
        pairbuf[pd] = ((d & 511) << 17) | sv;      // N <= 2^17
        int ps = atomicAdd(&curs[sv >> BSH], 1);
        srctmp[ps] = sv;
    }
}

// ---------------- P4c: per-bucket CSR build + degree isqrt (both sides) -------------
// grid = 2*nbuck: blocks [0,nbuck) dst-side CSR + di_isqrt; [nbuck,2*nbuck) src-side do_isqrt
__global__ __launch_bounds__(256) void p4c(const int* __restrict__ pairbuf,
                                           const int* __restrict__ srctmp,
                                           const int* __restrict__ based,
                                           const int* __restrict__ bases,
                                           int* __restrict__ indptr, int* __restrict__ colbuf,
                                           float* __restrict__ di_isqrt, float* __restrict__ do_isqrt,
                                           int N, int E, int nbuck) {
    __shared__ int cnt[512], lp[512], s[256];
    int t = threadIdx.x;
    if ((int)blockIdx.x >= nbuck) {
        // ---- src side: out-degree counts -> do_isqrt ----
        int b = blockIdx.x - nbuck;
        int nbase = b << BSH;
        int nn = min(512, N - nbase);
        cnt[t] = 0; cnt[t + 256] = 0;
        __syncthreads();
        int eb = bases[b], ee = bases[b + 1];
        for (int e = eb + t; e < ee; e += 256)
            atomicAdd(&cnt[srctmp[e] - nbase], 1);
        __syncthreads();
        for (int i = t; i < nn; i += 256)
            do_isqrt[nbase + i] = rsqrtf((float)max(cnt[i], 1));
        return;
    }
    // ---- dst side: CSR + di_isqrt ----
    int b = blockIdx.x;
    int nbase = b << BSH;
    int nn = min(512, N - nbase);
    cnt[t] = 0; cnt[t + 256] = 0;
    __syncthreads();
    int eb = based[b], ee = based[b + 1];
    for (int e = eb + t; e < ee; e += 256)
        atomicAdd(&cnt[pairbuf[e] >> 17], 1);
    __syncthreads();
    // exclusive scan over 512 counts (thread t owns 2t, 2t+1)
    int a0 = cnt[2 * t], a1 = cnt[2 * t + 1];
    int psum = a0 + a1;
    s[t] = psum;
    __syncthreads();
    for (int off = 1; off < 256; off <<= 1) {
        int v = (t >= off) ? s[t - off] : 0;
        __syncthreads();
        s[t] += v;
        __syncthreads();
    }
    int ebase = s[t] - psum;
    lp[2 * t] = ebase;
    lp[2 * t + 1] = ebase + a0;
    __syncthreads();
    for (int i = t; i < nn; i += 256) {
        indptr[nbase + i] = eb + lp[i];
        di_isqrt[nbase + i] = rsqrtf((float)max(cnt[i], 1));
    }
    if (b == 0 && t == 0) indptr[N] = E;
    __syncthreads();
    for (int e = eb + t; e < ee; e += 256) {
        int pk = pairbuf[e];
        int pos = atomicAdd(&lp[pk >> 17], 1);
        colbuf[eb + pos] = pk & 0x1FFFF;
    }
}

// ---------------- weight prep: bf16 transposed [col][K] ----------------
__global__ __launch_bounds__(256) void wprep(const float* __restrict__ W1, const float* __restrict__ W2,
                                             const float* __restrict__ W3, const float* __restrict__ Wm,
                                             unsigned short* __restrict__ W1t, unsigned short* __restrict__ W2t,
                                             unsigned short* __restrict__ W3t, unsigned short* __restrict__ Wmt) {
    int i = blockIdx.x * 256 + threadIdx.x;
    if (i < 256 * 64) { int k = i / 64, c = i % 64; W1t[c * 256 + k] = f2bf(W1[i]); return; }
    int j = i - 256 * 64;
    if (j < 64 * 64) { int k = j / 64, c = j % 64; W2t[c * 64 + k] = f2bf(W2[j]); return; }
    int j2 = j - 64 * 64;
    if (j2 < 64 * 64) { int k = j2 / 64, c = j2 % 64; W3t[c * 64 + k] = f2bf(W3[j2]); return; }
    int j3 = j2 - 64 * 64;
    if (j3 < 192 * 32) { int k = j3 / 32, c = j3 % 32; Wmt[c * 192 + k] = f2bf(Wm[j3]); }
}

// ---------------- MFMA GEMM (layer 1): out_bf16 = (X_f32 .* rs) @ Wt^T ----------------
template <int COLS, int K>
__global__ __launch_bounds__(256) void mgemm(
    const float* __restrict__ X, int ldx,
    const unsigned short* __restrict__ Wt,
    const float* __restrict__ rs,
    unsigned short* __restrict__ out, int ldo, int nrows) {
    constexpr int KC = 64;
    constexpr int NFRAG = COLS / 16;
    __shared__ unsigned short Al[64 * KC];
    __shared__ unsigned short Bl[COLS * KC];

    const int tid = threadIdx.x;
    const int wave = tid >> 6, lane = tid & 63;
    const int g = lane >> 4, lm = lane & 15;
    const int gr0 = blockIdx.x * 64;

    floatx4 acc[NFRAG];
    #pragma unroll
    for (int f = 0; f < NFRAG; ++f) acc[f] = (floatx4)0.f;

    for (int kc = 0; kc < K; kc += KC) {
        for (int c = tid; c < 64 * 8; c += 256) {
            int row = c >> 3, c8 = c & 7;
            int grow = gr0 + row;
            unsigned short v[8];
            if (grow < nrows) {
                const float* Xf = X + (size_t)grow * ldx + kc + c8 * 8;
                float sc = rs ? rs[grow] : 1.f;
                #pragma unroll
                for (int j = 0; j < 8; ++j) v[j] = f2bf(Xf[j] * sc);
            } else {
                #pragma unroll
                for (int j = 0; j < 8; ++j) v[j] = 0;
            }
            int off = (row * KC + c8 * 8) ^ ((row & 7) << 3);
            *(uint4*)&Al[off] = *(uint4*)v;
        }
        for (int c = tid; c < COLS * 8; c += 256) {
            int col = c >> 3, c8 = c & 7;
            uint4 raw = *(const uint4*)&Wt[(size_t)col * K + kc + c8 * 8];
            int off = (col * KC + c8 * 8) ^ ((col & 7) << 3);
            *(uint4*)&Bl[off] = raw;
        }
        __syncthreads();
        #pragma unroll
        for (int ks = 0; ks < 2; ++ks) {
            int arow = wave * 16 + lm;
            int aoff = (arow * KC + ks * 32 + g * 8) ^ ((arow & 7) << 3);
            shortx8 afrag = *(shortx8*)&Al[aoff];
            #pragma unroll
            for (int f = 0; f < NFRAG; ++f) {
                int col = f * 16 + lm;
                int boff = (col * KC + ks * 32 + g * 8) ^ ((col & 7) << 3);
                shortx8 bfrag = *(shortx8*)&Bl[boff];
                acc[f] = __builtin_amdgcn_mfma_f32_16x16x32_bf16(afrag, bfrag, acc[f], 0, 0, 0);
            }
        }
        __syncthreads();
    }
    #pragma unroll
    for (int f = 0; f < NFRAG; ++f) {
        #pragma unroll
        for (int r = 0; r < 4; ++r) {
            int grow = gr0 + wave * 16 + g * 4 + r;
            if (grow < nrows) out[(size_t)grow * ldo + f * 16 + lm] = f2bf(acc[f][r]);
        }
    }
}

// ---------------- fused gather + GEMM ----------------
// MODE 0: h = relu(agg(fin)*di + b); Hb[:,hoff] = h; out = (h .* do) @ Wt[64][64]^T  (tmp bf16 N*64)
// MODE 1: h3 = relu(agg(fin)*di + b)  (LDS only); out = [h1,h2 (Hb), h3] @ Wt[32][192]^T (P bf16 N*32)
template <int MODE>
__global__ __launch_bounds__(256) void gg_kernel(
    const int* __restrict__ indptr, const int* __restrict__ colbuf,
    const uint2* __restrict__ fin,            // bf16x4 rows [*, 16]
    const float* __restrict__ di, const float* __restrict__ dov,
    const float* __restrict__ bias,
    const unsigned short* __restrict__ Wt,    // [COLS][K]
    uint2* __restrict__ hb,                   // [N][32] uint2 (h1 | h2)
    int hoff,                                 // uint2 col offset for MODE0 write
    unsigned short* __restrict__ outb, int N) {
    constexpr int COLS = MODE ? 32 : 64;
    constexpr int NFRAG = COLS / 16;
    __shared__ unsigned short Al[64 * 64];
    __shared__ unsigned short Bl[COLS * 64];
    __shared__ uint2 Gl[64 * 16];

    const int tid = threadIdx.x;
    const int wave = tid >> 6, lane = tid & 63;
    const int g = lane >> 4, lm = lane & 15;
    const int gr0 = blockIdx.x * 64;

    // ---- gather phase: 16 lanes/node (uint2 = 4 cols), 4 passes ----
    #pragma unroll
    for (int rep = 0; rep < 4; ++rep) {
        int nl = rep * 16 + (tid >> 4);
        int j = tid & 15;
        int node = gr0 + nl;
        float a0 = 0.f, a1 = 0.f, a2 = 0.f, a3 = 0.f;
        float r0 = 0.f, r1 = 0.f, r2 = 0.f, r3 = 0.f;
        if (node < N) {
            int beg = indptr[node], end = indptr[node + 1];
            int e = beg;
            for (; e + 2 <= end; e += 2) {
                int c0 = colbuf[e], c1 = colbuf[e + 1];
                uint2 u0 = fin[(size_t)c0 * 16 + j];
                uint2 u1 = fin[(size_t)c1 * 16 + j];
                a0 += bf2f((unsigned short)(u0.x & 0xffff)) + bf2f((unsigned short)(u1.x & 0xffff));
                a1 += bf2f((unsigned short)(u0.x >> 16)) + bf2f((unsigned short)(u1.x >> 16));
                a2 += bf2f((unsigned short)(u0.y & 0xffff)) + bf2f((unsigned short)(u1.y & 0xffff));
                a3 += bf2f((unsigned short)(u0.y >> 16)) + bf2f((unsigned short)(u1.y >> 16));
            }
            if (e < end) {
                int c0 = colbuf[e];
                uint2 u0 = fin[(size_t)c0 * 16 + j];
                a0 += bf2f((unsigned short)(u0.x & 0xffff));
                a1 += bf2f((unsigned short)(u0.x >> 16));
                a2 += bf2f((unsigned short)(u0.y & 0xffff));
                a3 += bf2f((unsigned short)(u0.y >> 16));
            }
            float dval = di[node];
            float4 bb = *(const float4*)&bias[j * 4];
            r0 = fmaxf(a0 * dval + bb.x, 0.f);
            r1 = fmaxf(a1 * dval + bb.y, 0.f);
            r2 = fmaxf(a2 * dval + bb.z, 0.f);
            r3 = fmaxf(a3 * dval + bb.w, 0.f);
        }
        uint2 gv;
        gv.x = pack2(r0, r1);
        gv.y = pack2(r2, r3);
        Gl[nl * 16 + j] = gv;
        if (MODE == 0 && node < N) hb[(size_t)node * 32 + hoff + j] = gv;
    }
    __syncthreads();

    floatx4 acc[NFRAG];
    #pragma unroll
    for (int f = 0; f < NFRAG; ++f) acc[f] = (floatx4)0.f;

    constexpr int NCHUNK = MODE ? 3 : 1;
    for (int kc = 0; kc < NCHUNK; ++kc) {
        // stage A
        if (MODE == 0) {
            for (int c = tid; c < 64 * 16; c += 256) {
                int row = c >> 4, jj = c & 15;
                int grow = gr0 + row;
                float sc = (grow < N) ? dov[grow] : 0.f;
                uint2 gv = Gl[row * 16 + jj];
                uint2 o;
                o.x = pack2(bf2f((unsigned short)(gv.x & 0xffff)) * sc,
                            bf2f((unsigned short)(gv.x >> 16)) * sc);
                o.y = pack2(bf2f((unsigned short)(gv.y & 0xffff)) * sc,
                            bf2f((unsigned short)(gv.y >> 16)) * sc);
                int off = (row * 64 + jj * 4) ^ ((row & 7) << 3);
                *(uint2*)&Al[off] = o;
            }
        } else {
            for (int c = tid; c < 64 * 16; c += 256) {
                int row = c >> 4, jj = c & 15;
                int grow = gr0 + row;
                uint2 gv;
                if (kc < 2) {
                    gv = (grow < N) ? hb[(size_t)grow * 32 + kc * 16 + jj] : make_uint2(0u, 0u);
                } else {
                    gv = Gl[row * 16 + jj];
                }
                int off = (row * 64 + jj * 4) ^ ((row & 7) << 3);
                *(uint2*)&Al[off] = gv;
            }
        }
        // stage B chunk
        for (int c = tid; c < COLS * 8; c += 256) {
            int col = c >> 3, c8 = c & 7;
            uint4 raw = *(const uint4*)&Wt[(size_t)col * (MODE ? 192 : 64) + kc * 64 + c8 * 8];
            int off = (col * 64 + c8 * 8) ^ ((col & 7) << 3);
            *(uint4*)&Bl[off] = raw;
        }
        __syncthreads();
        #pragma unroll
        for (int ks = 0; ks < 2; ++ks) {
            int arow = wave * 16 + lm;
            int aoff = (arow * 64 + ks * 32 + g * 8) ^ ((arow & 7) << 3);
            shortx8 afrag = *(shortx8*)&Al[aoff];
            #pragma unroll
            for (int f = 0; f < NFRAG; ++f) {
                int col = f * 16 + lm;
                int boff = (col * 64 + ks * 32 + g * 8) ^ ((col & 7) << 3);
                shortx8 bfrag = *(shortx8*)&Bl[boff];
                acc[f] = __builtin_amdgcn_mfma_f32_16x16x32_bf16(afrag, bfrag, acc[f], 0, 0, 0);
            }
        }
        __syncthreads();
    }
    // epilogue
    #pragma unroll
    for (int f = 0; f < NFRAG; ++f) {
        #pragma unroll
        for (int r = 0; r < 4; ++r) {
            int grow = gr0 + wave * 16 + g * 4 + r;
            if (grow < N) outb[(size_t)grow * COLS + f * 16 + lm] = f2bf(acc[f][r]);
        }
    }
}

// ---------------- final gather: out[n] = sum_e P[col[e]] + bm  (f32 out) --------------
__global__ __launch_bounds__(256) void final_gather(
    const int* __restrict__ indptr, const int* __restrict__ colbuf,
    const uint2* __restrict__ P2,             // bf16x4 [*, 8]
    const float* __restrict__ bm,
    float* __restrict__ out, int N) {
    int j = threadIdx.x & 7;
    int node = blockIdx.x * 32 + (threadIdx.x >> 3);
    if (node >= N) return;
    int beg = indptr[node], end = indptr[node + 1];
    float a0 = 0.f, a1 = 0.f, a2 = 0.f, a3 = 0.f;
    int e = beg;
    for (; e + 2 <= end; e += 2) {
        int c0 = colbuf[e], c1 = colbuf[e + 1];
        uint2 u0 = P2[(size_t)c0 * 8 + j];
        uint2 u1 = P2[(size_t)c1 * 8 + j];
        a0 += bf2f((unsigned short)(u0.x & 0xffff)) + bf2f((unsigned short)(u1.x & 0xffff));
        a1 += bf2f((unsigned short)(u0.x >> 16)) + bf2f((unsigned short)(u1.x >> 16));
        a2 += bf2f((unsigned short)(u0.y & 0xffff)) + bf2f((unsigned short)(u1.y & 0xffff));
        a3 += bf2f((unsigned short)(u0.y >> 16)) + bf2f((unsigned short)(u1.y >> 16));
    }
    if (e < end) {
        int c0 = colbuf[e];
        uint2 u0 = P2[(size_t)c0 * 8 + j];
        a0 += bf2f((unsigned short)(u0.x & 0xffff));
        a1 += bf2f((unsigned short)(u0.x >> 16));
        a2 += bf2f((unsigned short)(u0.y & 0xffff));
        a3 += bf2f((unsigned short)(u0.y >> 16));
    }
    float4 bb = *(const float4*)&bm[j * 4];
    float4 o = make_float4(a0 + bb.x, a1 + bb.y, a2 + bb.z, a3 + bb.w);
    *(float4*)&out[(size_t)node * 32 + j * 4] = o;
}

// ---------------- launch ----------------
extern "C" void kernel_launch(void* const* d_in, const int* in_sizes, int n_in,
                              void* d_out, int out_size, void* d_ws, size_t ws_size,
                              hipStream_t stream) {
    const float* feat = (const float*)d_in[0];
    const int*   src  = (const int*)d_in[1];
    const int*   dst  = (const int*)d_in[2];
    const float* W1   = (const float*)d_in[3];
    const float* b1   = (const float*)d_in[4];
    const float* W2   = (const float*)d_in[5];
    const float* b2   = (const float*)d_in[6];
    const float* W3   = (const float*)d_in[7];
    const float* b3   = (const float*)d_in[8];
    const float* Wm   = (const float*)d_in[9];
    const float* bm   = (const float*)d_in[10];
    float* out = (float*)d_out;

    const int N = in_sizes[0] / IN_FEATS;   // 100000
    const int E = in_sizes[1];              // 1600000
    const int NBUCK = (N + 511) >> BSH;     // 196

    // workspace carve (256B-aligned regions)
    char* wsp = (char*)d_ws;
    auto alloc = [&](size_t bytes) {
        void* p = (void*)wsp;
        wsp += ((bytes + 255) / 256) * 256;
        return p;
    };
    int*   indptr   = (int*)alloc((size_t)(N + 1) * 4);
    int*   colbuf   = (int*)alloc((size_t)E * 4);
    int*   bhd      = (int*)alloc((size_t)NBLK * NB * 4);
    int*   bhs      = (int*)alloc((size_t)NBLK * NB * 4);
    int*   totd     = (int*)alloc(256 * 4);
    int*   tots     = (int*)alloc(256 * 4);
    int*   based    = (int*)alloc(257 * 4);
    int*   bases    = (int*)alloc(257 * 4);
    float* do_isqrt = (float*)alloc((size_t)N * 4);
    float* di_isqrt = (float*)alloc((size_t)N * 4);
    unsigned short* W1t = (unsigned short*)alloc(256 * 64 * 2);
    unsigned short* W2t = (unsigned short*)alloc(64 * 64 * 2);
    unsigned short* W3t = (unsigned short*)alloc(64 * 64 * 2);
    unsigned short* Wmt = (unsigned short*)alloc(192 * 32 * 2);
    uint2* Hb       = (uint2*)alloc((size_t)N * 32 * 8);      // [N][32] uint2 = h1|h2
    int*   pairbuf  = (int*)alloc((size_t)E * 4);             // packed; aliased by tmpA
    int*   srctmp   = (int*)alloc((size_t)E * 4);             // aliased by tmpA (2nd half)
    unsigned short* tmpA = (unsigned short*)pairbuf;          // N*64 bf16 = 12.8MB = E*8 exact
    unsigned short* tmpB = (unsigned short*)alloc((size_t)N * HID * 2);
    unsigned short* P    = (unsigned short*)alloc((size_t)N * OUTF * 2);

    // ---- CSR + degree build (no global atomics) ----
    p1_hist<<<NBLK, 256, 0, stream>>>(src, dst, E, bhd, bhs);
    p2a_tot<<<512, 256, 0, stream>>>(bhd, bhs, totd, tots, NBLK);
    p2b_scan<<<2, 256, 0, stream>>>(totd, tots, based, bases);
    p2c_off<<<512, 256, 0, stream>>>(bhd, bhs, based, bases, NBLK);
    p3_scatter<<<NBLK, 256, 0, stream>>>(src, dst, E, bhd, bhs, pairbuf, srctmp);
    p4c<<<2 * NBUCK, 256, 0, stream>>>(pairbuf, srctmp, based, bases, indptr, colbuf,
                                       di_isqrt, do_isqrt, N, E, NBUCK);
    wprep<<<120, 256, 0, stream>>>(W1, W2, W3, Wm, W1t, W2t, W3t, Wmt);

    const int GB = (N + 63) / 64;   // 1563
    // ---- layers (tmpA/tmpB ping-pong; pairbuf+srctmp dead after p4c) ----
    mgemm<HID, IN_FEATS><<<GB, 256, 0, stream>>>(feat, IN_FEATS, W1t, do_isqrt, tmpA, HID, N);
    gg_kernel<0><<<GB, 256, 0, stream>>>(indptr, colbuf, (const uint2*)tmpA, di_isqrt, do_isqrt,
                                         b1, W2t, Hb, 0, tmpB, N);
    gg_kernel<0><<<GB, 256, 0, stream>>>(indptr, colbuf, (const uint2*)tmpB, di_isqrt, do_isqrt,
                                         b2, W3t, Hb, 16, tmpA, N);
    gg_kernel<1><<<GB, 256, 0, stream>>>(indptr, colbuf, (const uint2*)tmpA, di_isqrt, nullptr,
                                         b3, Wmt, Hb, 0, P, N);
    final_gather<<<(N + 31) / 32, 256, 0, stream>>>(indptr, colbuf, (const uint2*)P, bm, out, N);
}

// Round 7
// 251.413 us; speedup vs baseline: 1.2374x; 1.2374x over previous
//
#include <hip/hip_runtime.h>

#define IN_FEATS 256
#define HID 64
#define OUTF 32
#define JK (3*HID)

#define NB   256   // buckets (allocated); actual used = (N+511)>>9
#define BSH  9     // bucket covers 512 nodes
#define NBLK 512   // edge-chunk blocks for hist/scatter
// NOTE: packed pairbuf assumes N <= 2^17 (src fits 17 bits). N=100000 here.

typedef __attribute__((ext_vector_type(4))) float floatx4;
typedef __attribute__((ext_vector_type(8))) short shortx8;

// ---------------- bf16 helpers (RNE) ----------------
__device__ inline unsigned short f2bf(float f) {
    unsigned u = __float_as_uint(f);
    unsigned r = (u + 0x7fffu + ((u >> 16) & 1u)) >> 16;
    return (unsigned short)r;
}
__device__ inline float bf2f(unsigned short u) {
    return __uint_as_float(((unsigned)u) << 16);
}
__device__ inline unsigned pack2(float a, float b) {
    return (unsigned)f2bf(a) | ((unsigned)f2bf(b) << 16);
}
__device__ inline void acc8(uint4 u, float* a) {
    a[0] += bf2f((unsigned short)(u.x & 0xffff)); a[1] += bf2f((unsigned short)(u.x >> 16));
    a[2] += bf2f((unsigned short)(u.y & 0xffff)); a[3] += bf2f((unsigned short)(u.y >> 16));
    a[4] += bf2f((unsigned short)(u.z & 0xffff)); a[5] += bf2f((unsigned short)(u.z >> 16));
    a[6] += bf2f((unsigned short)(u.w & 0xffff)); a[7] += bf2f((unsigned short)(u.w >> 16));
}

// ---------------- P1: per-block LDS histograms over dst-buckets and src-buckets ----
__global__ __launch_bounds__(256) void p1_hist(const int* __restrict__ src,
                                               const int* __restrict__ dst, int E,
                                               int* __restrict__ bhd, int* __restrict__ bhs) {
    __shared__ int hd[NB], hs[NB];
    int b = blockIdx.x;
    for (int t = threadIdx.x; t < NB; t += 256) { hd[t] = 0; hs[t] = 0; }
    __syncthreads();
    int cb = (E + NBLK - 1) / NBLK;
    int beg = b * cb, end = min(beg + cb, E);
    for (int e = beg + threadIdx.x; e < end; e += 256) {
        atomicAdd(&hd[dst[e] >> BSH], 1);
        atomicAdd(&hs[src[e] >> BSH], 1);
    }
    __syncthreads();
    for (int t = threadIdx.x; t < NB; t += 256) {
        bhd[b * NB + t] = hd[t];
        bhs[b * NB + t] = hs[t];
    }
}

// ---------------- P2a: per-(side,bucket) totals over block-histograms ----------------
__global__ __launch_bounds__(256) void p2a_tot(const int* __restrict__ bhd,
                                               const int* __restrict__ bhs,
                                               int* __restrict__ totd, int* __restrict__ tots,
                                               int nblk) {
    __shared__ int s[256];
    int side = blockIdx.x >> 8;     // grid = 512
    int t = blockIdx.x & 255;
    const int* bh = side ? bhs : bhd;
    int acc = 0;
    for (int k = threadIdx.x; k < nblk; k += 256) acc += bh[k * NB + t];
    s[threadIdx.x] = acc;
    __syncthreads();
    for (int off = 128; off > 0; off >>= 1) {
        if (threadIdx.x < off) s[threadIdx.x] += s[threadIdx.x + off];
        __syncthreads();
    }
    if (threadIdx.x == 0) (side ? tots : totd)[t] = s[0];
}

// ---------------- P2b: exclusive scan over bucket totals -> based/bases ----------------
__global__ __launch_bounds__(256) void p2b_scan(const int* __restrict__ totd,
                                                const int* __restrict__ tots,
                                                int* __restrict__ based, int* __restrict__ bases) {
    __shared__ int s[256];
    const int* tot = blockIdx.x ? tots : totd;
    int* bb = blockIdx.x ? bases : based;
    int t = threadIdx.x;
    int v = tot[t];
    s[t] = v;
    __syncthreads();
    for (int off = 1; off < 256; off <<= 1) {
        int u = (t >= off) ? s[t - off] : 0;
        __syncthreads();
        s[t] += u;
        __syncthreads();
    }
    bb[t] = s[t] - v;
    if (t == 255) bb[256] = s[255];
}

// ---------------- P2c: per-bucket prefix over blocks (in place) ----------------
__global__ __launch_bounds__(256) void p2c_off(int* __restrict__ bhd, int* __restrict__ bhs,
                                               const int* __restrict__ based,
                                               const int* __restrict__ bases, int nblk) {
    __shared__ int s[256];
    int side = blockIdx.x >> 8;     // grid = 512
    int t = blockIdx.x & 255;
    int* bh = side ? bhs : bhd;
    int carry = (side ? bases : based)[t];
    for (int k0 = 0; k0 < nblk; k0 += 256) {
        int k = k0 + threadIdx.x;
        int v = (k < nblk) ? bh[k * NB + t] : 0;
        s[threadIdx.x] = v;
        __syncthreads();
        for (int off = 1; off < 256; off <<= 1) {
            int u = (threadIdx.x >= off) ? s[threadIdx.x - off] : 0;
            __syncthreads();
            s[threadIdx.x] += u;
            __syncthreads();
        }
        if (k < nblk) bh[k * NB + t] = carry + s[threadIdx.x] - v;
        int tot = s[255];
        __syncthreads();
        carry += tot;
    }
}

// ---------------- P3: partition edges by bucket (LDS cursors, packed pairs) ----------
__global__ __launch_bounds__(256) void p3_scatter(const int* __restrict__ src,
                                                  const int* __restrict__ dst, int E,
                                                  const int* __restrict__ bhd,
                                                  const int* __restrict__ bhs,
                                                  int* __restrict__ pairbuf,
                                                  int* __restrict__ srctmp) {
    __shared__ int curd[NB], curs[NB];
    int b = blockIdx.x;
    for (int t = threadIdx.x; t < NB; t += 256) {
        curd[t] = bhd[b * NB + t];
        curs[t] = bhs[b * NB + t];
    }
    __syncthreads();
    int cb = (E + NBLK - 1) / NBLK;
    int beg = b * cb, end = min(beg + cb, E);
    for (int e = beg + threadIdx.x; e < end; e += 256) {
        int d = dst[e], sv = src[e];
        int pd = atomicAdd(&curd[d >> BSH], 1);
        pairbuf[pd] = ((d & 511) << 17) | sv;      // N <= 2^17
        int ps = atomicAdd(&curs[sv >> BSH], 1);
        srctmp[ps] = sv;
    }
}

// ---------------- P4c: per-bucket CSR build + degree isqrt (both sides) -------------
__global__ __launch_bounds__(256) void p4c(const int* __restrict__ pairbuf,
                                           const int* __restrict__ srctmp,
                                           const int* __restrict__ based,
                                           const int* __restrict__ bases,
                                           int* __restrict__ indptr, int* __restrict__ colbuf,
                                           float* __restrict__ di_isqrt, float* __restrict__ do_isqrt,
                                           int N, int E, int nbuck) {
    __shared__ int cnt[512], lp[512], s[256];
    int t = threadIdx.x;
    if ((int)blockIdx.x >= nbuck) {
        int b = blockIdx.x - nbuck;
        int nbase = b << BSH;
        int nn = min(512, N - nbase);
        cnt[t] = 0; cnt[t + 256] = 0;
        __syncthreads();
        int eb = bases[b], ee = bases[b + 1];
        for (int e = eb + t; e < ee; e += 256)
            atomicAdd(&cnt[srctmp[e] - nbase], 1);
        __syncthreads();
        for (int i = t; i < nn; i += 256)
            do_isqrt[nbase + i] = rsqrtf((float)max(cnt[i], 1));
        return;
    }
    int b = blockIdx.x;
    int nbase = b << BSH;
    int nn = min(512, N - nbase);
    cnt[t] = 0; cnt[t + 256] = 0;
    __syncthreads();
    int eb = based[b], ee = based[b + 1];
    for (int e = eb + t; e < ee; e += 256)
        atomicAdd(&cnt[pairbuf[e] >> 17], 1);
    __syncthreads();
    int a0 = cnt[2 * t], a1 = cnt[2 * t + 1];
    int psum = a0 + a1;
    s[t] = psum;
    __syncthreads();
    for (int off = 1; off < 256; off <<= 1) {
        int v = (t >= off) ? s[t - off] : 0;
        __syncthreads();
        s[t] += v;
        __syncthreads();
    }
    int ebase = s[t] - psum;
    lp[2 * t] = ebase;
    lp[2 * t + 1] = ebase + a0;
    __syncthreads();
    for (int i = t; i < nn; i += 256) {
        indptr[nbase + i] = eb + lp[i];
        di_isqrt[nbase + i] = rsqrtf((float)max(cnt[i], 1));
    }
    if (b == 0 && t == 0) indptr[N] = E;
    __syncthreads();
    for (int e = eb + t; e < ee; e += 256) {
        int pk = pairbuf[e];
        int pos = atomicAdd(&lp[pk >> 17], 1);
        colbuf[eb + pos] = pk & 0x1FFFF;
    }
}

// ---------------- weight prep: bf16 transposed [col][K] ----------------
__global__ __launch_bounds__(256) void wprep(const float* __restrict__ W1, const float* __restrict__ W2,
                                             const float* __restrict__ W3, const float* __restrict__ Wm,
                                             unsigned short* __restrict__ W1t, unsigned short* __restrict__ W2t,
                                             unsigned short* __restrict__ W3t, unsigned short* __restrict__ Wmt) {
    int i = blockIdx.x * 256 + threadIdx.x;
    if (i < 256 * 64) { int k = i / 64, c = i % 64; W1t[c * 256 + k] = f2bf(W1[i]); return; }
    int j = i - 256 * 64;
    if (j < 64 * 64) { int k = j / 64, c = j % 64; W2t[c * 64 + k] = f2bf(W2[j]); return; }
    int j2 = j - 64 * 64;
    if (j2 < 64 * 64) { int k = j2 / 64, c = j2 % 64; W3t[c * 64 + k] = f2bf(W3[j2]); return; }
    int j3 = j2 - 64 * 64;
    if (j3 < 192 * 32) { int k = j3 / 32, c = j3 % 32; Wmt[c * 192 + k] = f2bf(Wm[j3]); }
}

// ---------------- MFMA GEMM: out_bf16[nrows][COLS] = (X .* rs) @ Wt^T ----------------
// SRC_F32: X is f32; else X is bf16 (ldx in elements either way). Wt is bf16 [COLS][K].
template <int COLS, int K, bool SRC_F32>
__global__ __launch_bounds__(256) void mgemm(
    const void* __restrict__ Xv, int ldx,
    const unsigned short* __restrict__ Wt,
    const float* __restrict__ rs,
    unsigned short* __restrict__ out, int ldo, int nrows) {
    constexpr int KC = 64;
    constexpr int NFRAG = COLS / 16;
    __shared__ unsigned short Al[64 * KC];
    __shared__ unsigned short Bl[COLS * KC];

    const int tid = threadIdx.x;
    const int wave = tid >> 6, lane = tid & 63;
    const int g = lane >> 4, lm = lane & 15;
    const int gr0 = blockIdx.x * 64;

    floatx4 acc[NFRAG];
    #pragma unroll
    for (int f = 0; f < NFRAG; ++f) acc[f] = (floatx4)0.f;

    for (int kc = 0; kc < K; kc += KC) {
        for (int c = tid; c < 64 * 8; c += 256) {
            int row = c >> 3, c8 = c & 7;
            int grow = gr0 + row;
            unsigned short v[8];
            if (grow < nrows) {
                if (SRC_F32) {
                    const float* Xf = (const float*)Xv + (size_t)grow * ldx + kc + c8 * 8;
                    float sc = rs ? rs[grow] : 1.f;
                    #pragma unroll
                    for (int j = 0; j < 8; ++j) v[j] = f2bf(Xf[j] * sc);
                } else {
                    const unsigned short* Xh = (const unsigned short*)Xv + (size_t)grow * ldx + kc + c8 * 8;
                    uint4 raw = *(const uint4*)Xh;
                    unsigned short* rp = (unsigned short*)&raw;
                    if (rs) {
                        float sc = rs[grow];
                        #pragma unroll
                        for (int j = 0; j < 8; ++j) v[j] = f2bf(bf2f(rp[j]) * sc);
                    } else {
                        #pragma unroll
                        for (int j = 0; j < 8; ++j) v[j] = rp[j];
                    }
                }
            } else {
                #pragma unroll
                for (int j = 0; j < 8; ++j) v[j] = 0;
            }
            int off = (row * KC + c8 * 8) ^ ((row & 7) << 3);
            *(uint4*)&Al[off] = *(uint4*)v;
        }
        for (int c = tid; c < COLS * 8; c += 256) {
            int col = c >> 3, c8 = c & 7;
            uint4 raw = *(const uint4*)&Wt[(size_t)col * K + kc + c8 * 8];
            int off = (col * KC + c8 * 8) ^ ((col & 7) << 3);
            *(uint4*)&Bl[off] = raw;
        }
        __syncthreads();
        #pragma unroll
        for (int ks = 0; ks < 2; ++ks) {
            int arow = wave * 16 + lm;
            int aoff = (arow * KC + ks * 32 + g * 8) ^ ((arow & 7) << 3);
            shortx8 afrag = *(shortx8*)&Al[aoff];
            #pragma unroll
            for (int f = 0; f < NFRAG; ++f) {
                int col = f * 16 + lm;
                int boff = (col * KC + ks * 32 + g * 8) ^ ((col & 7) << 3);
                shortx8 bfrag = *(shortx8*)&Bl[boff];
                acc[f] = __builtin_amdgcn_mfma_f32_16x16x32_bf16(afrag, bfrag, acc[f], 0, 0, 0);
            }
        }
        __syncthreads();
    }
    #pragma unroll
    for (int f = 0; f < NFRAG; ++f) {
        #pragma unroll
        for (int r = 0; r < 4; ++r) {
            int grow = gr0 + wave * 16 + g * 4 + r;
            if (grow < nrows) out[(size_t)grow * ldo + f * 16 + lm] = f2bf(acc[f][r]);
        }
    }
}

// ---------------- standalone gather (HID=64): 8 lanes/node, uint4 rows ----------------
// hout[node][col_off + 8j .. +7] = relu(di*sum + bias), bf16 packed, row stride ldh (uint4)
__global__ __launch_bounds__(256) void gatherH(
    const int* __restrict__ indptr, const int* __restrict__ colbuf,
    const uint4* __restrict__ fin,            // [*, 8] uint4 rows (64 bf16)
    const float* __restrict__ di, const float* __restrict__ bias,
    uint4* __restrict__ hout, int ldh, int coff, int N) {
    int j = threadIdx.x & 7;
    int node = blockIdx.x * 32 + (threadIdx.x >> 3);
    if (node >= N) return;
    int beg = indptr[node], end = indptr[node + 1];
    float a[8] = {};
    int e = beg;
    for (; e + 2 <= end; e += 2) {
        int c0 = colbuf[e], c1 = colbuf[e + 1];
        uint4 u0 = fin[(size_t)c0 * 8 + j];
        uint4 u1 = fin[(size_t)c1 * 8 + j];
        acc8(u0, a); acc8(u1, a);
    }
    if (e < end) acc8(fin[(size_t)colbuf[e] * 8 + j], a);
    float dval = di[node];
    float4 b0 = *(const float4*)&bias[j * 8];
    float4 b1 = *(const float4*)&bias[j * 8 + 4];
    float r[8];
    r[0] = fmaxf(a[0] * dval + b0.x, 0.f); r[1] = fmaxf(a[1] * dval + b0.y, 0.f);
    r[2] = fmaxf(a[2] * dval + b0.z, 0.f); r[3] = fmaxf(a[3] * dval + b0.w, 0.f);
    r[4] = fmaxf(a[4] * dval + b1.x, 0.f); r[5] = fmaxf(a[5] * dval + b1.y, 0.f);
    r[6] = fmaxf(a[6] * dval + b1.z, 0.f); r[7] = fmaxf(a[7] * dval + b1.w, 0.f);
    uint4 o;
    o.x = pack2(r[0], r[1]); o.y = pack2(r[2], r[3]);
    o.z = pack2(r[4], r[5]); o.w = pack2(r[6], r[7]);
    hout[(size_t)node * ldh + coff + j] = o;
}

// ---------------- final gather: out[n][32] = sum_e P[col[e]] + bm  (f32 out) ----------
__global__ __launch_bounds__(256) void final_gather(
    const int* __restrict__ indptr, const int* __restrict__ colbuf,
    const uint4* __restrict__ P4,             // [*, 4] uint4 rows (32 bf16)
    const float* __restrict__ bm,
    float* __restrict__ out, int N) {
    int j = threadIdx.x & 3;
    int node = blockIdx.x * 64 + (threadIdx.x >> 2);
    if (node >= N) return;
    int beg = indptr[node], end = indptr[node + 1];
    float a[8] = {};
    int e = beg;
    for (; e + 2 <= end; e += 2) {
        int c0 = colbuf[e], c1 = colbuf[e + 1];
        uint4 u0 = P4[(size_t)c0 * 4 + j];
        uint4 u1 = P4[(size_t)c1 * 4 + j];
        acc8(u0, a); acc8(u1, a);
    }
    if (e < end) acc8(P4[(size_t)colbuf[e] * 4 + j], a);
    float4 b0 = *(const float4*)&bm[j * 8];
    float4 b1 = *(const float4*)&bm[j * 8 + 4];
    float4 o0 = make_float4(a[0] + b0.x, a[1] + b0.y, a[2] + b0.z, a[3] + b0.w);
    float4 o1 = make_float4(a[4] + b1.x, a[5] + b1.y, a[6] + b1.z, a[7] + b1.w);
    *(float4*)&out[(size_t)node * 32 + j * 8] = o0;
    *(float4*)&out[(size_t)node * 32 + j * 8 + 4] = o1;
}

// ---------------- launch ----------------
extern "C" void kernel_launch(void* const* d_in, const int* in_sizes, int n_in,
                              void* d_out, int out_size, void* d_ws, size_t ws_size,
                              hipStream_t stream) {
    const float* feat = (const float*)d_in[0];
    const int*   src  = (const int*)d_in[1];
    const int*   dst  = (const int*)d_in[2];
    const float* W1   = (const float*)d_in[3];
    const float* b1   = (const float*)d_in[4];
    const float* W2   = (const float*)d_in[5];
    const float* b2   = (const float*)d_in[6];
    const float* W3   = (const float*)d_in[7];
    const float* b3   = (const float*)d_in[8];
    const float* Wm   = (const float*)d_in[9];
    const float* bm   = (const float*)d_in[10];
    float* out = (float*)d_out;

    const int N = in_sizes[0] / IN_FEATS;   // 100000
    const int E = in_sizes[1];              // 1600000
    const int NBUCK = (N + 511) >> BSH;     // 196

    // workspace carve (256B-aligned regions)
    char* wsp = (char*)d_ws;
    auto alloc = [&](size_t bytes) {
        void* p = (void*)wsp;
        wsp += ((bytes + 255) / 256) * 256;
        return p;
    };
    int*   indptr   = (int*)alloc((size_t)(N + 1) * 4);
    int*   colbuf   = (int*)alloc((size_t)E * 4);
    int*   bhd      = (int*)alloc((size_t)NBLK * NB * 4);
    int*   bhs      = (int*)alloc((size_t)NBLK * NB * 4);
    int*   totd     = (int*)alloc(256 * 4);
    int*   tots     = (int*)alloc(256 * 4);
    int*   based    = (int*)alloc(257 * 4);
    int*   bases    = (int*)alloc(257 * 4);
    float* do_isqrt = (float*)alloc((size_t)N * 4);
    float* di_isqrt = (float*)alloc((size_t)N * 4);
    unsigned short* W1t = (unsigned short*)alloc(256 * 64 * 2);
    unsigned short* W2t = (unsigned short*)alloc(64 * 64 * 2);
    unsigned short* W3t = (unsigned short*)alloc(64 * 64 * 2);
    unsigned short* Wmt = (unsigned short*)alloc(192 * 32 * 2);
    unsigned short* Hb  = (unsigned short*)alloc((size_t)N * JK * 2);  // [N][192] bf16
    int*   pairbuf  = (int*)alloc((size_t)E * 4);   // packed; + srctmp = tmp after p4c
    int*   srctmp   = (int*)alloc((size_t)E * 4);
    unsigned short* tmp = (unsigned short*)pairbuf; // N*64 bf16 = 12.8MB = both regions
    unsigned short* P   = (unsigned short*)alloc((size_t)N * OUTF * 2);

    // ---- CSR + degree build (no global atomics) ----
    p1_hist<<<NBLK, 256, 0, stream>>>(src, dst, E, bhd, bhs);
    p2a_tot<<<512, 256, 0, stream>>>(bhd, bhs, totd, tots, NBLK);
    p2b_scan<<<2, 256, 0, stream>>>(totd, tots, based, bases);
    p2c_off<<<512, 256, 0, stream>>>(bhd, bhs, based, bases, NBLK);
    p3_scatter<<<NBLK, 256, 0, stream>>>(src, dst, E, bhd, bhs, pairbuf, srctmp);
    p4c<<<2 * NBUCK, 256, 0, stream>>>(pairbuf, srctmp, based, bases, indptr, colbuf,
                                       di_isqrt, do_isqrt, N, E, NBUCK);
    wprep<<<120, 256, 0, stream>>>(W1, W2, W3, Wm, W1t, W2t, W3t, Wmt);

    const int GB = (N + 63) / 64;      // 1563
    const int GGB = (N + 31) / 32;     // 3125
    // ---- layers (single tmp buffer; Hb accumulates h1|h2|h3) ----
    mgemm<HID, IN_FEATS, true><<<GB, 256, 0, stream>>>(feat, IN_FEATS, W1t, do_isqrt, tmp, HID, N);
    gatherH<<<GGB, 256, 0, stream>>>(indptr, colbuf, (const uint4*)tmp, di_isqrt, b1,
                                     (uint4*)Hb, 24, 0, N);
    mgemm<HID, HID, false><<<GB, 256, 0, stream>>>(Hb, JK, W2t, do_isqrt, tmp, HID, N);
    gatherH<<<GGB, 256, 0, stream>>>(indptr, colbuf, (const uint4*)tmp, di_isqrt, b2,
                                     (uint4*)Hb, 24, 8, N);
    mgemm<HID, HID, false><<<GB, 256, 0, stream>>>(Hb + HID, JK, W3t, do_isqrt, tmp, HID, N);
    gatherH<<<GGB, 256, 0, stream>>>(indptr, colbuf, (const uint4*)tmp, di_isqrt, b3,
                                     (uint4*)Hb, 24, 16, N);
    // JK projection BEFORE final aggregation (linearity): P = Hb @ Wm
    mgemm<OUTF, JK, false><<<GB, 256, 0, stream>>>(Hb, JK, Wmt, nullptr, P, OUTF, N);
    final_gather<<<(N + 63) / 64, 256, 0, stream>>>(indptr, colbuf, (const uint4*)P, bm, out, N);
}

// Round 8
// 244.598 us; speedup vs baseline: 1.2719x; 1.0279x over previous
//
#include <hip/hip_runtime.h>

#define IN_FEATS 256
#define HID 64
#define OUTF 32
#define JK (3*HID)

#define NB   256
#define BSH  9
#define NBLK 512
// NOTE: packed pairbuf assumes N <= 2^17. N=100000 here.

typedef __attribute__((ext_vector_type(4))) float floatx4;
typedef __attribute__((ext_vector_type(8))) short shortx8;

__device__ inline unsigned short f2bf(float f) {
    unsigned u = __float_as_uint(f);
    unsigned r = (u + 0x7fffu + ((u >> 16) & 1u)) >> 16;
    return (unsigned short)r;
}
__device__ inline float bf2f(unsigned short u) {
    return __uint_as_float(((unsigned)u) << 16);
}
__device__ inline unsigned pack2(float a, float b) {
    return (unsigned)f2bf(a) | ((unsigned)f2bf(b) << 16);
}
__device__ inline void acc8(uint4 u, float* a) {
    a[0] += bf2f((unsigned short)(u.x & 0xffff)); a[1] += bf2f((unsigned short)(u.x >> 16));
    a[2] += bf2f((unsigned short)(u.y & 0xffff)); a[3] += bf2f((unsigned short)(u.y >> 16));
    a[4] += bf2f((unsigned short)(u.z & 0xffff)); a[5] += bf2f((unsigned short)(u.z >> 16));
    a[6] += bf2f((unsigned short)(u.w & 0xffff)); a[7] += bf2f((unsigned short)(u.w >> 16));
}

// ---------------- P1: per-block LDS histograms ----------------
__global__ __launch_bounds__(256) void p1_hist(const int* __restrict__ src,
                                               const int* __restrict__ dst, int E,
                                               int* __restrict__ bhd, int* __restrict__ bhs) {
    __shared__ int hd[NB], hs[NB];
    int b = blockIdx.x;
    for (int t = threadIdx.x; t < NB; t += 256) { hd[t] = 0; hs[t] = 0; }
    __syncthreads();
    int cb = (E + NBLK - 1) / NBLK;
    int beg = b * cb, end = min(beg + cb, E);
    for (int e = beg + threadIdx.x; e < end; e += 256) {
        atomicAdd(&hd[dst[e] >> BSH], 1);
        atomicAdd(&hs[src[e] >> BSH], 1);
    }
    __syncthreads();
    for (int t = threadIdx.x; t < NB; t += 256) {
        bhd[b * NB + t] = hd[t];
        bhs[b * NB + t] = hs[t];
    }
}

// ---------------- P2a (+wprep grid-fused) ----------------
__global__ __launch_bounds__(256) void p2a_tot(const int* __restrict__ bhd,
                                               const int* __restrict__ bhs,
                                               int* __restrict__ totd, int* __restrict__ tots,
                                               int nblk,
                                               const float* __restrict__ W1, const float* __restrict__ W2,
                                               const float* __restrict__ W3, const float* __restrict__ Wm,
                                               unsigned short* __restrict__ W1t, unsigned short* __restrict__ W2t,
                                               unsigned short* __restrict__ W3t, unsigned short* __restrict__ Wmt) {
    if ((int)blockIdx.x >= 512) {
        int i = (blockIdx.x - 512) * 256 + threadIdx.x;
        if (i < 256 * 64) { int k = i / 64, c = i % 64; W1t[c * 256 + k] = f2bf(W1[i]); return; }
        int j = i - 256 * 64;
        if (j < 64 * 64) { int k = j / 64, c = j % 64; W2t[c * 64 + k] = f2bf(W2[j]); return; }
        int j2 = j - 64 * 64;
        if (j2 < 64 * 64) { int k = j2 / 64, c = j2 % 64; W3t[c * 64 + k] = f2bf(W3[j2]); return; }
        int j3 = j2 - 64 * 64;
        if (j3 < 192 * 32) { int k = j3 / 32, c = j3 % 32; Wmt[c * 192 + k] = f2bf(Wm[j3]); }
        return;
    }
    __shared__ int s[256];
    int side = blockIdx.x >> 8;
    int t = blockIdx.x & 255;
    const int* bh = side ? bhs : bhd;
    int acc = 0;
    for (int k = threadIdx.x; k < nblk; k += 256) acc += bh[k * NB + t];
    s[threadIdx.x] = acc;
    __syncthreads();
    for (int off = 128; off > 0; off >>= 1) {
        if (threadIdx.x < off) s[threadIdx.x] += s[threadIdx.x + off];
        __syncthreads();
    }
    if (threadIdx.x == 0) (side ? tots : totd)[t] = s[0];
}

// ---------------- P2b ----------------
__global__ __launch_bounds__(256) void p2b_scan(const int* __restrict__ totd,
                                                const int* __restrict__ tots,
                                                int* __restrict__ based, int* __restrict__ bases) {
    __shared__ int s[256];
    const int* tot = blockIdx.x ? tots : totd;
    int* bb = blockIdx.x ? bases : based;
    int t = threadIdx.x;
    int v = tot[t];
    s[t] = v;
    __syncthreads();
    for (int off = 1; off < 256; off <<= 1) {
        int u = (t >= off) ? s[t - off] : 0;
        __syncthreads();
        s[t] += u;
        __syncthreads();
    }
    bb[t] = s[t] - v;
    if (t == 255) bb[256] = s[255];
}

// ---------------- P2c ----------------
__global__ __launch_bounds__(256) void p2c_off(int* __restrict__ bhd, int* __restrict__ bhs,
                                               const int* __restrict__ based,
                                               const int* __restrict__ bases, int nblk) {
    __shared__ int s[256];
    int side = blockIdx.x >> 8;
    int t = blockIdx.x & 255;
    int* bh = side ? bhs : bhd;
    int carry = (side ? bases : based)[t];
    for (int k0 = 0; k0 < nblk; k0 += 256) {
        int k = k0 + threadIdx.x;
        int v = (k < nblk) ? bh[k * NB + t] : 0;
        s[threadIdx.x] = v;
        __syncthreads();
        for (int off = 1; off < 256; off <<= 1) {
            int u = (threadIdx.x >= off) ? s[threadIdx.x - off] : 0;
            __syncthreads();
            s[threadIdx.x] += u;
            __syncthreads();
        }
        if (k < nblk) bh[k * NB + t] = carry + s[threadIdx.x] - v;
        int tot = s[255];
        __syncthreads();
        carry += tot;
    }
}

// ---------------- P3M: grid-fused {edge partition} + {UNSCALED layer-1 GEMM} --------
// blocks [0,NBLK): p3 scatter. blocks [NBLK,NBLK+gemmb): tmp = feat @ W1t^T (no scale;
// do_isqrt row-scale commutes with GEMM and is applied by the scaleT pass after p4c).
__global__ __launch_bounds__(256) void p3m(
    const int* __restrict__ src, const int* __restrict__ dst, int E,
    const int* __restrict__ bhd, const int* __restrict__ bhs,
    int* __restrict__ pairbuf, int* __restrict__ srctmp,
    const float* __restrict__ feat, const unsigned short* __restrict__ W1t,
    unsigned short* __restrict__ outb, int nrows) {
    __shared__ int curd[NB], curs[NB];
    __shared__ unsigned short Al[64 * 64];
    __shared__ unsigned short Bl[64 * 64];

    if ((int)blockIdx.x < NBLK) {
        int b = blockIdx.x;
        for (int t = threadIdx.x; t < NB; t += 256) {
            curd[t] = bhd[b * NB + t];
            curs[t] = bhs[b * NB + t];
        }
        __syncthreads();
        int cb = (E + NBLK - 1) / NBLK;
        int beg = b * cb, end = min(beg + cb, E);
        for (int e = beg + threadIdx.x; e < end; e += 256) {
            int d = dst[e], sv = src[e];
            int pd = atomicAdd(&curd[d >> BSH], 1);
            pairbuf[pd] = ((d & 511) << 17) | sv;
            int ps = atomicAdd(&curs[sv >> BSH], 1);
            srctmp[ps] = sv;
        }
        return;
    }
    const int tid = threadIdx.x;
    const int wave = tid >> 6, lane = tid & 63;
    const int g = lane >> 4, lm = lane & 15;
    const int gr0 = (blockIdx.x - NBLK) * 64;

    floatx4 acc[4];
    #pragma unroll
    for (int f = 0; f < 4; ++f) acc[f] = (floatx4)0.f;

    for (int kc = 0; kc < IN_FEATS; kc += 64) {
        for (int c = tid; c < 64 * 8; c += 256) {
            int row = c >> 3, c8 = c & 7;
            int grow = gr0 + row;
            unsigned short v[8];
            if (grow < nrows) {
                const float* Xf = feat + (size_t)grow * IN_FEATS + kc + c8 * 8;
                #pragma unroll
                for (int j = 0; j < 8; ++j) v[j] = f2bf(Xf[j]);
            } else {
                #pragma unroll
                for (int j = 0; j < 8; ++j) v[j] = 0;
            }
            int off = (row * 64 + c8 * 8) ^ ((row & 7) << 3);
            *(uint4*)&Al[off] = *(uint4*)v;
        }
        for (int c = tid; c < 64 * 8; c += 256) {
            int col = c >> 3, c8 = c & 7;
            uint4 raw = *(const uint4*)&W1t[(size_t)col * IN_FEATS + kc + c8 * 8];
            int off = (col * 64 + c8 * 8) ^ ((col & 7) << 3);
            *(uint4*)&Bl[off] = raw;
        }
        __syncthreads();
        #pragma unroll
        for (int ks = 0; ks < 2; ++ks) {
            int arow = wave * 16 + lm;
            int aoff = (arow * 64 + ks * 32 + g * 8) ^ ((arow & 7) << 3);
            shortx8 afrag = *(shortx8*)&Al[aoff];
            #pragma unroll
            for (int f = 0; f < 4; ++f) {
                int col = f * 16 + lm;
                int boff = (col * 64 + ks * 32 + g * 8) ^ ((col & 7) << 3);
                shortx8 bfrag = *(shortx8*)&Bl[boff];
                acc[f] = __builtin_amdgcn_mfma_f32_16x16x32_bf16(afrag, bfrag, acc[f], 0, 0, 0);
            }
        }
        __syncthreads();
    }
    #pragma unroll
    for (int f = 0; f < 4; ++f) {
        #pragma unroll
        for (int r = 0; r < 4; ++r) {
            int grow = gr0 + wave * 16 + g * 4 + r;
            if (grow < nrows) outb[(size_t)grow * 64 + f * 16 + lm] = f2bf(acc[f][r]);
        }
    }
}

// ---------------- P4c: per-bucket CSR build + degree isqrt ----------------
__global__ __launch_bounds__(256) void p4c(const int* __restrict__ pairbuf,
                                           const int* __restrict__ srctmp,
                                           const int* __restrict__ based,
                                           const int* __restrict__ bases,
                                           int* __restrict__ indptr, int* __restrict__ colbuf,
                                           float* __restrict__ di_isqrt, float* __restrict__ do_isqrt,
                                           int N, int E, int nbuck) {
    __shared__ int cnt[512], lp[512], s[256];
    int t = threadIdx.x;
    if ((int)blockIdx.x >= nbuck) {
        int b = blockIdx.x - nbuck;
        int nbase = b << BSH;
        int nn = min(512, N - nbase);
        cnt[t] = 0; cnt[t + 256] = 0;
        __syncthreads();
        int eb = bases[b], ee = bases[b + 1];
        for (int e = eb + t; e < ee; e += 256)
            atomicAdd(&cnt[srctmp[e] - nbase], 1);
        __syncthreads();
        for (int i = t; i < nn; i += 256)
            do_isqrt[nbase + i] = rsqrtf((float)max(cnt[i], 1));
        return;
    }
    int b = blockIdx.x;
    int nbase = b << BSH;
    int nn = min(512, N - nbase);
    cnt[t] = 0; cnt[t + 256] = 0;
    __syncthreads();
    int eb = based[b], ee = based[b + 1];
    for (int e = eb + t; e < ee; e += 256)
        atomicAdd(&cnt[pairbuf[e] >> 17], 1);
    __syncthreads();
    int a0 = cnt[2 * t], a1 = cnt[2 * t + 1];
    int psum = a0 + a1;
    s[t] = psum;
    __syncthreads();
    for (int off = 1; off < 256; off <<= 1) {
        int v = (t >= off) ? s[t - off] : 0;
        __syncthreads();
        s[t] += v;
        __syncthreads();
    }
    int ebase = s[t] - psum;
    lp[2 * t] = ebase;
    lp[2 * t + 1] = ebase + a0;
    __syncthreads();
    for (int i = t; i < nn; i += 256) {
        indptr[nbase + i] = eb + lp[i];
        di_isqrt[nbase + i] = rsqrtf((float)max(cnt[i], 1));
    }
    if (b == 0 && t == 0) indptr[N] = E;
    __syncthreads();
    for (int e = eb + t; e < ee; e += 256) {
        int pk = pairbuf[e];
        int pos = atomicAdd(&lp[pk >> 17], 1);
        colbuf[eb + pos] = pk & 0x1FFFF;
    }
}

// ---------------- scaleT: tmp[v][:] *= do_isqrt[v]  (bf16 in place) ----------------
__global__ __launch_bounds__(256) void scaleT(uint4* __restrict__ tmp,
                                              const float* __restrict__ dov, int N) {
    int j = threadIdx.x & 7;
    int node = blockIdx.x * 32 + (threadIdx.x >> 3);
    if (node >= N) return;
    float sc = dov[node];
    uint4 u = tmp[(size_t)node * 8 + j];
    uint4 o;
    o.x = pack2(bf2f((unsigned short)(u.x & 0xffff)) * sc, bf2f((unsigned short)(u.x >> 16)) * sc);
    o.y = pack2(bf2f((unsigned short)(u.y & 0xffff)) * sc, bf2f((unsigned short)(u.y >> 16)) * sc);
    o.z = pack2(bf2f((unsigned short)(u.z & 0xffff)) * sc, bf2f((unsigned short)(u.z >> 16)) * sc);
    o.w = pack2(bf2f((unsigned short)(u.w & 0xffff)) * sc, bf2f((unsigned short)(u.w >> 16)) * sc);
    tmp[(size_t)node * 8 + j] = o;
}

// ---------------- MFMA GEMM (layers 2,3,P) ----------------
template <int COLS, int K>
__global__ __launch_bounds__(256) void mgemm(
    const unsigned short* __restrict__ X, int ldx,
    const unsigned short* __restrict__ Wt,
    const float* __restrict__ rs,
    unsigned short* __restrict__ out, int ldo, int nrows) {
    constexpr int KC = 64;
    constexpr int NFRAG = COLS / 16;
    __shared__ unsigned short Al[64 * KC];
    __shared__ unsigned short Bl[COLS * KC];

    const int tid = threadIdx.x;
    const int wave = tid >> 6, lane = tid & 63;
    const int g = lane >> 4, lm = lane & 15;
    const int gr0 = blockIdx.x * 64;

    floatx4 acc[NFRAG];
    #pragma unroll
    for (int f = 0; f < NFRAG; ++f) acc[f] = (floatx4)0.f;

    for (int kc = 0; kc < K; kc += KC) {
        for (int c = tid; c < 64 * 8; c += 256) {
            int row = c >> 3, c8 = c & 7;
            int grow = gr0 + row;
            unsigned short v[8];
            if (grow < nrows) {
                uint4 raw = *(const uint4*)(X + (size_t)grow * ldx + kc + c8 * 8);
                unsigned short* rp = (unsigned short*)&raw;
                if (rs) {
                    float sc = rs[grow];
                    #pragma unroll
                    for (int j = 0; j < 8; ++j) v[j] = f2bf(bf2f(rp[j]) * sc);
                } else {
                    #pragma unroll
                    for (int j = 0; j < 8; ++j) v[j] = rp[j];
                }
            } else {
                #pragma unroll
                for (int j = 0; j < 8; ++j) v[j] = 0;
            }
            int off = (row * KC + c8 * 8) ^ ((row & 7) << 3);
            *(uint4*)&Al[off] = *(uint4*)v;
        }
        for (int c = tid; c < COLS * 8; c += 256) {
            int col = c >> 3, c8 = c & 7;
            uint4 raw = *(const uint4*)&Wt[(size_t)col * K + kc + c8 * 8];
            int off = (col * KC + c8 * 8) ^ ((col & 7) << 3);
            *(uint4*)&Bl[off] = raw;
        }
        __syncthreads();
        #pragma unroll
        for (int ks = 0; ks < 2; ++ks) {
            int arow = wave * 16 + lm;
            int aoff = (arow * KC + ks * 32 + g * 8) ^ ((arow & 7) << 3);
            shortx8 afrag = *(shortx8*)&Al[aoff];
            #pragma unroll
            for (int f = 0; f < NFRAG; ++f) {
                int col = f * 16 + lm;
                int boff = (col * KC + ks * 32 + g * 8) ^ ((col & 7) << 3);
                shortx8 bfrag = *(shortx8*)&Bl[boff];
                acc[f] = __builtin_amdgcn_mfma_f32_16x16x32_bf16(afrag, bfrag, acc[f], 0, 0, 0);
            }
        }
        __syncthreads();
    }
    #pragma unroll
    for (int f = 0; f < NFRAG; ++f) {
        #pragma unroll
        for (int r = 0; r < 4; ++r) {
            int grow = gr0 + wave * 16 + g * 4 + r;
            if (grow < nrows) out[(size_t)grow * ldo + f * 16 + lm] = f2bf(acc[f][r]);
        }
    }
}

// ---------------- standalone gather (HID=64): 8 lanes/node, uint4 rows, int4 colbuf --
__global__ __launch_bounds__(256) void gatherH(
    const int* __restrict__ indptr, const int* __restrict__ colbuf,
    const uint4* __restrict__ fin,
    const float* __restrict__ di, const float* __restrict__ bias,
    uint4* __restrict__ hout, int ldh, int coff, int N) {
    int j = threadIdx.x & 7;
    int node = blockIdx.x * 32 + (threadIdx.x >> 3);
    if (node >= N) return;
    int beg = indptr[node], end = indptr[node + 1];
    float a[8] = {};
    int e = beg;
    for (; e + 4 <= end; e += 4) {
        int4 cc = *(const int4*)&colbuf[e];
        uint4 u0 = fin[(size_t)cc.x * 8 + j];
        uint4 u1 = fin[(size_t)cc.y * 8 + j];
        uint4 u2 = fin[(size_t)cc.z * 8 + j];
        uint4 u3 = fin[(size_t)cc.w * 8 + j];
        acc8(u0, a); acc8(u1, a); acc8(u2, a); acc8(u3, a);
    }
    for (; e < end; ++e) acc8(fin[(size_t)colbuf[e] * 8 + j], a);
    float dval = di[node];
    float4 b0 = *(const float4*)&bias[j * 8];
    float4 b1 = *(const float4*)&bias[j * 8 + 4];
    float r[8];
    r[0] = fmaxf(a[0] * dval + b0.x, 0.f); r[1] = fmaxf(a[1] * dval + b0.y, 0.f);
    r[2] = fmaxf(a[2] * dval + b0.z, 0.f); r[3] = fmaxf(a[3] * dval + b0.w, 0.f);
    r[4] = fmaxf(a[4] * dval + b1.x, 0.f); r[5] = fmaxf(a[5] * dval + b1.y, 0.f);
    r[6] = fmaxf(a[6] * dval + b1.z, 0.f); r[7] = fmaxf(a[7] * dval + b1.w, 0.f);
    uint4 o;
    o.x = pack2(r[0], r[1]); o.y = pack2(r[2], r[3]);
    o.z = pack2(r[4], r[5]); o.w = pack2(r[6], r[7]);
    hout[(size_t)node * ldh + coff + j] = o;
}

// ---------------- final gather ----------------
__global__ __launch_bounds__(256) void final_gather(
    const int* __restrict__ indptr, const int* __restrict__ colbuf,
    const uint4* __restrict__ P4,
    const float* __restrict__ bm,
    float* __restrict__ out, int N) {
    int j = threadIdx.x & 3;
    int node = blockIdx.x * 64 + (threadIdx.x >> 2);
    if (node >= N) return;
    int beg = indptr[node], end = indptr[node + 1];
    float a[8] = {};
    int e = beg;
    for (; e + 4 <= end; e += 4) {
        int4 cc = *(const int4*)&colbuf[e];
        uint4 u0 = P4[(size_t)cc.x * 4 + j];
        uint4 u1 = P4[(size_t)cc.y * 4 + j];
        uint4 u2 = P4[(size_t)cc.z * 4 + j];
        uint4 u3 = P4[(size_t)cc.w * 4 + j];
        acc8(u0, a); acc8(u1, a); acc8(u2, a); acc8(u3, a);
    }
    for (; e < end; ++e) acc8(P4[(size_t)colbuf[e] * 4 + j], a);
    float4 b0 = *(const float4*)&bm[j * 8];
    float4 b1 = *(const float4*)&bm[j * 8 + 4];
    float4 o0 = make_float4(a[0] + b0.x, a[1] + b0.y, a[2] + b0.z, a[3] + b0.w);
    float4 o1 = make_float4(a[4] + b1.x, a[5] + b1.y, a[6] + b1.z, a[7] + b1.w);
    *(float4*)&out[(size_t)node * 32 + j * 8] = o0;
    *(float4*)&out[(size_t)node * 32 + j * 8 + 4] = o1;
}

// ---------------- launch ----------------
extern "C" void kernel_launch(void* const* d_in, const int* in_sizes, int n_in,
                              void* d_out, int out_size, void* d_ws, size_t ws_size,
                              hipStream_t stream) {
    const float* feat = (const float*)d_in[0];
    const int*   src  = (const int*)d_in[1];
    const int*   dst  = (const int*)d_in[2];
    const float* W1   = (const float*)d_in[3];
    const float* b1   = (const float*)d_in[4];
    const float* W2   = (const float*)d_in[5];
    const float* b2   = (const float*)d_in[6];
    const float* W3   = (const float*)d_in[7];
    const float* b3   = (const float*)d_in[8];
    const float* Wm   = (const float*)d_in[9];
    const float* bm   = (const float*)d_in[10];
    float* out = (float*)d_out;

    const int N = in_sizes[0] / IN_FEATS;   // 100000
    const int E = in_sizes[1];              // 1600000
    const int NBUCK = (N + 511) >> BSH;     // 196

    char* wsp = (char*)d_ws;
    auto alloc = [&](size_t bytes) {
        void* p = (void*)wsp;
        wsp += ((bytes + 255) / 256) * 256;
        return p;
    };
    int*   indptr   = (int*)alloc((size_t)(N + 1) * 4);
    int*   colbuf   = (int*)alloc((size_t)E * 4);
    int*   bhd      = (int*)alloc((size_t)NBLK * NB * 4);
    int*   bhs      = (int*)alloc((size_t)NBLK * NB * 4);
    int*   totd     = (int*)alloc(256 * 4);
    int*   tots     = (int*)alloc(256 * 4);
    int*   based    = (int*)alloc(257 * 4);
    int*   bases    = (int*)alloc(257 * 4);
    float* do_isqrt = (float*)alloc((size_t)N * 4);
    float* di_isqrt = (float*)alloc((size_t)N * 4);
    unsigned short* W1t = (unsigned short*)alloc(256 * 64 * 2);
    unsigned short* W2t = (unsigned short*)alloc(64 * 64 * 2);
    unsigned short* W3t = (unsigned short*)alloc(64 * 64 * 2);
    unsigned short* Wmt = (unsigned short*)alloc(192 * 32 * 2);
    unsigned short* Hb  = (unsigned short*)alloc((size_t)N * JK * 2);
    int*   pairbuf  = (int*)alloc((size_t)E * 4);
    int*   srctmp   = (int*)alloc((size_t)E * 4);
    unsigned short* tmp = (unsigned short*)alloc((size_t)N * HID * 2); // un-aliased (overlap safety)
    unsigned short* P   = (unsigned short*)alloc((size_t)N * OUTF * 2);

    const int GB = (N + 63) / 64;      // 1563
    const int GGB = (N + 31) / 32;     // 3125

    p1_hist<<<NBLK, 256, 0, stream>>>(src, dst, E, bhd, bhs);
    p2a_tot<<<512 + 120, 256, 0, stream>>>(bhd, bhs, totd, tots, NBLK,
                                           W1, W2, W3, Wm, W1t, W2t, W3t, Wmt);
    p2b_scan<<<2, 256, 0, stream>>>(totd, tots, based, bases);
    p2c_off<<<512, 256, 0, stream>>>(bhd, bhs, based, bases, NBLK);
    // overlapped: edge partition (latency-bound) + unscaled layer-1 GEMM (BW-bound)
    p3m<<<NBLK + GB, 256, 0, stream>>>(src, dst, E, bhd, bhs, pairbuf, srctmp,
                                       feat, W1t, tmp, N);
    p4c<<<2 * NBUCK, 256, 0, stream>>>(pairbuf, srctmp, based, bases, indptr, colbuf,
                                       di_isqrt, do_isqrt, N, E, NBUCK);
    // apply deferred do_isqrt row scale: (s.x)@W == s.(x@W)
    scaleT<<<GGB, 256, 0, stream>>>((uint4*)tmp, do_isqrt, N);

    gatherH<<<GGB, 256, 0, stream>>>(indptr, colbuf, (const uint4*)tmp, di_isqrt, b1,
                                     (uint4*)Hb, 24, 0, N);
    mgemm<HID, HID><<<GB, 256, 0, stream>>>(Hb, JK, W2t, do_isqrt, tmp, HID, N);
    gatherH<<<GGB, 256, 0, stream>>>(indptr, colbuf, (const uint4*)tmp, di_isqrt, b2,
                                     (uint4*)Hb, 24, 8, N);
    mgemm<HID, HID><<<GB, 256, 0, stream>>>(Hb + HID, JK, W3t, do_isqrt, tmp, HID, N);
    gatherH<<<GGB, 256, 0, stream>>>(indptr, colbuf, (const uint4*)tmp, di_isqrt, b3,
                                     (uint4*)Hb, 24, 16, N);
    mgemm<OUTF, JK><<<GB, 256, 0, stream>>>(Hb, JK, Wmt, nullptr, P, OUTF, N);
    final_gather<<<(N + 63) / 64, 256, 0, stream>>>(indptr, colbuf, (const uint4*)P, bm, out, N);
}

// Round 9
// 235.960 us; speedup vs baseline: 1.3184x; 1.0366x over previous
//
#include <hip/hip_runtime.h>

#define IN_FEATS 256
#define HID 64
#define OUTF 32
#define JK (3*HID)

#define NB    128   // bucket slots (used: 98)
#define BSH   10    // bucket covers 1024 nodes
#define NBLK2 256   // edge-chunk blocks for hist/scatter
// NOTE: packed pairbuf assumes N <= 2^17 (src 17 bits, local dst 10 bits). N=100000.

typedef __attribute__((ext_vector_type(4))) float floatx4;
typedef __attribute__((ext_vector_type(8))) short shortx8;

__device__ inline unsigned short f2bf(float f) {
    unsigned u = __float_as_uint(f);
    unsigned r = (u + 0x7fffu + ((u >> 16) & 1u)) >> 16;
    return (unsigned short)r;
}
__device__ inline float bf2f(unsigned short u) {
    return __uint_as_float(((unsigned)u) << 16);
}
__device__ inline unsigned pack2(float a, float b) {
    return (unsigned)f2bf(a) | ((unsigned)f2bf(b) << 16);
}
__device__ inline void acc8(uint4 u, float* a) {
    a[0] += bf2f((unsigned short)(u.x & 0xffff)); a[1] += bf2f((unsigned short)(u.x >> 16));
    a[2] += bf2f((unsigned short)(u.y & 0xffff)); a[3] += bf2f((unsigned short)(u.y >> 16));
    a[4] += bf2f((unsigned short)(u.z & 0xffff)); a[5] += bf2f((unsigned short)(u.z >> 16));
    a[6] += bf2f((unsigned short)(u.w & 0xffff)); a[7] += bf2f((unsigned short)(u.w >> 16));
}
__device__ inline void acc8s(uint4 u, float* a, float s) {
    a[0] = fmaf(bf2f((unsigned short)(u.x & 0xffff)), s, a[0]);
    a[1] = fmaf(bf2f((unsigned short)(u.x >> 16)), s, a[1]);
    a[2] = fmaf(bf2f((unsigned short)(u.y & 0xffff)), s, a[2]);
    a[3] = fmaf(bf2f((unsigned short)(u.y >> 16)), s, a[3]);
    a[4] = fmaf(bf2f((unsigned short)(u.z & 0xffff)), s, a[4]);
    a[5] = fmaf(bf2f((unsigned short)(u.z >> 16)), s, a[5]);
    a[6] = fmaf(bf2f((unsigned short)(u.w & 0xffff)), s, a[6]);
    a[7] = fmaf(bf2f((unsigned short)(u.w >> 16)), s, a[7]);
}

// chunk bounds: cb multiple of 4 so int4 loads stay 16B-aligned from an aligned base
__device__ inline void chunk_bounds(int E, int b, int& beg, int& end) {
    int cb = ((E + NBLK2 - 1) / NBLK2 + 3) & ~3;
    beg = b * cb;
    end = min(beg + cb, E);
}

// ---------------- P1: per-block LDS histograms (int4 edge loads) ----------------
__global__ __launch_bounds__(256) void p1_hist(const int* __restrict__ src,
                                               const int* __restrict__ dst, int E,
                                               int* __restrict__ bhd, int* __restrict__ bhs) {
    __shared__ int hd[NB], hs[NB];
    int b = blockIdx.x;
    for (int t = threadIdx.x; t < NB; t += 256) { hd[t] = 0; hs[t] = 0; }
    __syncthreads();
    int beg, end;
    chunk_bounds(E, b, beg, end);
    int e = beg + threadIdx.x * 4;
    for (; e + 4 <= end; e += 1024) {
        int4 dd = *(const int4*)&dst[e];
        int4 ss = *(const int4*)&src[e];
        atomicAdd(&hd[dd.x >> BSH], 1); atomicAdd(&hd[dd.y >> BSH], 1);
        atomicAdd(&hd[dd.z >> BSH], 1); atomicAdd(&hd[dd.w >> BSH], 1);
        atomicAdd(&hs[ss.x >> BSH], 1); atomicAdd(&hs[ss.y >> BSH], 1);
        atomicAdd(&hs[ss.z >> BSH], 1); atomicAdd(&hs[ss.w >> BSH], 1);
    }
    for (; e < end; ++e) {
        atomicAdd(&hd[dst[e] >> BSH], 1);
        atomicAdd(&hs[src[e] >> BSH], 1);
    }
    __syncthreads();
    for (int t = threadIdx.x; t < NB; t += 256) {
        bhd[b * NB + t] = hd[t];
        bhs[b * NB + t] = hs[t];
    }
}

// ---------------- P2a (+wprep grid-fused) ----------------
__global__ __launch_bounds__(256) void p2a_tot(const int* __restrict__ bhd,
                                               const int* __restrict__ bhs,
                                               int* __restrict__ totd, int* __restrict__ tots,
                                               int nblk,
                                               const float* __restrict__ W1, const float* __restrict__ W2,
                                               const float* __restrict__ W3, const float* __restrict__ Wm,
                                               unsigned short* __restrict__ W1t, unsigned short* __restrict__ W2t,
                                               unsigned short* __restrict__ W3t, unsigned short* __restrict__ Wmt) {
    if ((int)blockIdx.x >= 2 * NB) {
        int i = (blockIdx.x - 2 * NB) * 256 + threadIdx.x;
        if (i < 256 * 64) { int k = i / 64, c = i % 64; W1t[c * 256 + k] = f2bf(W1[i]); return; }
        int j = i - 256 * 64;
        if (j < 64 * 64) { int k = j / 64, c = j % 64; W2t[c * 64 + k] = f2bf(W2[j]); return; }
        int j2 = j - 64 * 64;
        if (j2 < 64 * 64) { int k = j2 / 64, c = j2 % 64; W3t[c * 64 + k] = f2bf(W3[j2]); return; }
        int j3 = j2 - 64 * 64;
        if (j3 < 192 * 32) { int k = j3 / 32, c = j3 % 32; Wmt[c * 192 + k] = f2bf(Wm[j3]); }
        return;
    }
    __shared__ int s[256];
    int side = blockIdx.x >> 7;
    int t = blockIdx.x & (NB - 1);
    const int* bh = side ? bhs : bhd;
    int acc = 0;
    for (int k = threadIdx.x; k < nblk; k += 256) acc += bh[k * NB + t];
    s[threadIdx.x] = acc;
    __syncthreads();
    for (int off = 128; off > 0; off >>= 1) {
        if (threadIdx.x < off) s[threadIdx.x] += s[threadIdx.x + off];
        __syncthreads();
    }
    if (threadIdx.x == 0) (side ? tots : totd)[t] = s[0];
}

// ---------------- P2b: exclusive scan over NB bucket totals ----------------
__global__ __launch_bounds__(128) void p2b_scan(const int* __restrict__ totd,
                                                const int* __restrict__ tots,
                                                int* __restrict__ based, int* __restrict__ bases) {
    __shared__ int s[NB];
    const int* tot = blockIdx.x ? tots : totd;
    int* bb = blockIdx.x ? bases : based;
    int t = threadIdx.x;
    int v = tot[t];
    s[t] = v;
    __syncthreads();
    for (int off = 1; off < NB; off <<= 1) {
        int u = (t >= off) ? s[t - off] : 0;
        __syncthreads();
        s[t] += u;
        __syncthreads();
    }
    bb[t] = s[t] - v;
    if (t == NB - 1) bb[NB] = s[NB - 1];
}

// ---------------- P2c: per-bucket prefix over blocks (in place) ----------------
__global__ __launch_bounds__(256) void p2c_off(int* __restrict__ bhd, int* __restrict__ bhs,
                                               const int* __restrict__ based,
                                               const int* __restrict__ bases, int nblk) {
    __shared__ int s[256];
    int side = blockIdx.x >> 7;
    int t = blockIdx.x & (NB - 1);
    int* bh = side ? bhs : bhd;
    int carry = (side ? bases : based)[t];
    for (int k0 = 0; k0 < nblk; k0 += 256) {
        int k = k0 + threadIdx.x;
        int v = (k < nblk) ? bh[k * NB + t] : 0;
        s[threadIdx.x] = v;
        __syncthreads();
        for (int off = 1; off < 256; off <<= 1) {
            int u = (threadIdx.x >= off) ? s[threadIdx.x - off] : 0;
            __syncthreads();
            s[threadIdx.x] += u;
            __syncthreads();
        }
        if (k < nblk) bh[k * NB + t] = carry + s[threadIdx.x] - v;
        int tot = s[255];
        __syncthreads();
        carry += tot;
    }
}

// ---------------- P3M: grid-fused {edge partition} + {UNSCALED layer-1 GEMM} --------
__global__ __launch_bounds__(256) void p3m(
    const int* __restrict__ src, const int* __restrict__ dst, int E,
    const int* __restrict__ bhd, const int* __restrict__ bhs,
    int* __restrict__ pairbuf, int* __restrict__ srctmp,
    const float* __restrict__ feat, const unsigned short* __restrict__ W1t,
    unsigned short* __restrict__ outb, int nrows) {
    __shared__ int curd[NB], curs[NB];
    __shared__ unsigned short Al[64 * 64];
    __shared__ unsigned short Bl[64 * 64];

    if ((int)blockIdx.x < NBLK2) {
        int b = blockIdx.x;
        for (int t = threadIdx.x; t < NB; t += 256) {
            curd[t] = bhd[b * NB + t];
            curs[t] = bhs[b * NB + t];
        }
        __syncthreads();
        int beg, end;
        chunk_bounds(E, b, beg, end);
        int e = beg + threadIdx.x * 4;
        for (; e + 4 <= end; e += 1024) {
            int4 dd = *(const int4*)&dst[e];
            int4 ss = *(const int4*)&src[e];
            int p0 = atomicAdd(&curd[dd.x >> BSH], 1); pairbuf[p0] = ((dd.x & 1023) << 17) | ss.x;
            int p1 = atomicAdd(&curd[dd.y >> BSH], 1); pairbuf[p1] = ((dd.y & 1023) << 17) | ss.y;
            int p2 = atomicAdd(&curd[dd.z >> BSH], 1); pairbuf[p2] = ((dd.z & 1023) << 17) | ss.z;
            int p3 = atomicAdd(&curd[dd.w >> BSH], 1); pairbuf[p3] = ((dd.w & 1023) << 17) | ss.w;
            int q0 = atomicAdd(&curs[ss.x >> BSH], 1); srctmp[q0] = ss.x;
            int q1 = atomicAdd(&curs[ss.y >> BSH], 1); srctmp[q1] = ss.y;
            int q2 = atomicAdd(&curs[ss.z >> BSH], 1); srctmp[q2] = ss.z;
            int q3 = atomicAdd(&curs[ss.w >> BSH], 1); srctmp[q3] = ss.w;
        }
        for (; e < end; ++e) {
            int d = dst[e], sv = src[e];
            int pd = atomicAdd(&curd[d >> BSH], 1);
            pairbuf[pd] = ((d & 1023) << 17) | sv;
            int ps = atomicAdd(&curs[sv >> BSH], 1);
            srctmp[ps] = sv;
        }
        return;
    }
    const int tid = threadIdx.x;
    const int wave = tid >> 6, lane = tid & 63;
    const int g = lane >> 4, lm = lane & 15;
    const int gr0 = (blockIdx.x - NBLK2) * 64;

    floatx4 acc[4];
    #pragma unroll
    for (int f = 0; f < 4; ++f) acc[f] = (floatx4)0.f;

    for (int kc = 0; kc < IN_FEATS; kc += 64) {
        for (int c = tid; c < 64 * 8; c += 256) {
            int row = c >> 3, c8 = c & 7;
            int grow = gr0 + row;
            unsigned short v[8];
            if (grow < nrows) {
                const float* Xf = feat + (size_t)grow * IN_FEATS + kc + c8 * 8;
                #pragma unroll
                for (int j = 0; j < 8; ++j) v[j] = f2bf(Xf[j]);
            } else {
                #pragma unroll
                for (int j = 0; j < 8; ++j) v[j] = 0;
            }
            int off = (row * 64 + c8 * 8) ^ ((row & 7) << 3);
            *(uint4*)&Al[off] = *(uint4*)v;
        }
        for (int c = tid; c < 64 * 8; c += 256) {
            int col = c >> 3, c8 = c & 7;
            uint4 raw = *(const uint4*)&W1t[(size_t)col * IN_FEATS + kc + c8 * 8];
            int off = (col * 64 + c8 * 8) ^ ((col & 7) << 3);
            *(uint4*)&Bl[off] = raw;
        }
        __syncthreads();
        #pragma unroll
        for (int ks = 0; ks < 2; ++ks) {
            int arow = wave * 16 + lm;
            int aoff = (arow * 64 + ks * 32 + g * 8) ^ ((arow & 7) << 3);
            shortx8 afrag = *(shortx8*)&Al[aoff];
            #pragma unroll
            for (int f = 0; f < 4; ++f) {
                int col = f * 16 + lm;
                int boff = (col * 64 + ks * 32 + g * 8) ^ ((col & 7) << 3);
                shortx8 bfrag = *(shortx8*)&Bl[boff];
                acc[f] = __builtin_amdgcn_mfma_f32_16x16x32_bf16(afrag, bfrag, acc[f], 0, 0, 0);
            }
        }
        __syncthreads();
    }
    #pragma unroll
    for (int f = 0; f < 4; ++f) {
        #pragma unroll
        for (int r = 0; r < 4; ++r) {
            int grow = gr0 + wave * 16 + g * 4 + r;
            if (grow < nrows) outb[(size_t)grow * 64 + f * 16 + lm] = f2bf(acc[f][r]);
        }
    }
}

// ---------------- P4c: per-bucket CSR build + degree isqrt (1024-node buckets) ------
__global__ __launch_bounds__(256) void p4c(const int* __restrict__ pairbuf,
                                           const int* __restrict__ srctmp,
                                           const int* __restrict__ based,
                                           const int* __restrict__ bases,
                                           int* __restrict__ indptr, int* __restrict__ colbuf,
                                           float* __restrict__ di_isqrt, float* __restrict__ do_isqrt,
                                           int N, int E, int nbuck) {
    __shared__ int cnt[1024], lp[1024], s[256];
    int t = threadIdx.x;
    if ((int)blockIdx.x >= nbuck) {
        int b = blockIdx.x - nbuck;
        int nbase = b << BSH;
        int nn = min(1024, N - nbase);
        #pragma unroll
        for (int i = 0; i < 4; ++i) cnt[t + 256 * i] = 0;
        __syncthreads();
        int eb = bases[b], ee = bases[b + 1];
        for (int e = eb + t; e < ee; e += 256)
            atomicAdd(&cnt[srctmp[e] - nbase], 1);
        __syncthreads();
        for (int i = t; i < nn; i += 256)
            do_isqrt[nbase + i] = rsqrtf((float)max(cnt[i], 1));
        return;
    }
    int b = blockIdx.x;
    int nbase = b << BSH;
    int nn = min(1024, N - nbase);
    #pragma unroll
    for (int i = 0; i < 4; ++i) cnt[t + 256 * i] = 0;
    __syncthreads();
    int eb = based[b], ee = based[b + 1];
    for (int e = eb + t; e < ee; e += 256)
        atomicAdd(&cnt[pairbuf[e] >> 17], 1);
    __syncthreads();
    // exclusive scan over 1024 counts (thread t owns 4t..4t+3)
    int c0 = cnt[4 * t], c1 = cnt[4 * t + 1], c2 = cnt[4 * t + 2], c3 = cnt[4 * t + 3];
    int psum = c0 + c1 + c2 + c3;
    s[t] = psum;
    __syncthreads();
    for (int off = 1; off < 256; off <<= 1) {
        int v = (t >= off) ? s[t - off] : 0;
        __syncthreads();
        s[t] += v;
        __syncthreads();
    }
    int base = s[t] - psum;
    lp[4 * t] = base;
    lp[4 * t + 1] = base + c0;
    lp[4 * t + 2] = base + c0 + c1;
    lp[4 * t + 3] = base + c0 + c1 + c2;
    __syncthreads();
    for (int i = t; i < nn; i += 256) {
        indptr[nbase + i] = eb + lp[i];
        di_isqrt[nbase + i] = rsqrtf((float)max(cnt[i], 1));
    }
    if (b == 0 && t == 0) indptr[N] = E;
    __syncthreads();
    for (int e = eb + t; e < ee; e += 256) {
        int pk = pairbuf[e];
        int pos = atomicAdd(&lp[pk >> 17], 1);
        colbuf[eb + pos] = pk & 0x1FFFF;
    }
}

// ---------------- MFMA GEMM (layers 2,3,P) ----------------
template <int COLS, int K>
__global__ __launch_bounds__(256) void mgemm(
    const unsigned short* __restrict__ X, int ldx,
    const unsigned short* __restrict__ Wt,
    const float* __restrict__ rs,
    unsigned short* __restrict__ out, int ldo, int nrows) {
    constexpr int KC = 64;
    constexpr int NFRAG = COLS / 16;
    __shared__ unsigned short Al[64 * KC];
    __shared__ unsigned short Bl[COLS * KC];

    const int tid = threadIdx.x;
    const int wave = tid >> 6, lane = tid & 63;
    const int g = lane >> 4, lm = lane & 15;
    const int gr0 = blockIdx.x * 64;

    floatx4 acc[NFRAG];
    #pragma unroll
    for (int f = 0; f < NFRAG; ++f) acc[f] = (floatx4)0.f;

    for (int kc = 0; kc < K; kc += KC) {
        for (int c = tid; c < 64 * 8; c += 256) {
            int row = c >> 3, c8 = c & 7;
            int grow = gr0 + row;
            unsigned short v[8];
            if (grow < nrows) {
                uint4 raw = *(const uint4*)(X + (size_t)grow * ldx + kc + c8 * 8);
                unsigned short* rp = (unsigned short*)&raw;
                if (rs) {
                    float sc = rs[grow];
                    #pragma unroll
                    for (int j = 0; j < 8; ++j) v[j] = f2bf(bf2f(rp[j]) * sc);
                } else {
                    #pragma unroll
                    for (int j = 0; j < 8; ++j) v[j] = rp[j];
                }
            } else {
                #pragma unroll
                for (int j = 0; j < 8; ++j) v[j] = 0;
            }
            int off = (row * KC + c8 * 8) ^ ((row & 7) << 3);
            *(uint4*)&Al[off] = *(uint4*)v;
        }
        for (int c = tid; c < COLS * 8; c += 256) {
            int col = c >> 3, c8 = c & 7;
            uint4 raw = *(const uint4*)&Wt[(size_t)col * K + kc + c8 * 8];
            int off = (col * KC + c8 * 8) ^ ((col & 7) << 3);
            *(uint4*)&Bl[off] = raw;
        }
        __syncthreads();
        #pragma unroll
        for (int ks = 0; ks < 2; ++ks) {
            int arow = wave * 16 + lm;
            int aoff = (arow * KC + ks * 32 + g * 8) ^ ((arow & 7) << 3);
            shortx8 afrag = *(shortx8*)&Al[aoff];
            #pragma unroll
            for (int f = 0; f < NFRAG; ++f) {
                int col = f * 16 + lm;
                int boff = (col * KC + ks * 32 + g * 8) ^ ((col & 7) << 3);
                shortx8 bfrag = *(shortx8*)&Bl[boff];
                acc[f] = __builtin_amdgcn_mfma_f32_16x16x32_bf16(afrag, bfrag, acc[f], 0, 0, 0);
            }
        }
        __syncthreads();
    }
    #pragma unroll
    for (int f = 0; f < NFRAG; ++f) {
        #pragma unroll
        for (int r = 0; r < 4; ++r) {
            int grow = gr0 + wave * 16 + g * 4 + r;
            if (grow < nrows) out[(size_t)grow * ldo + f * 16 + lm] = f2bf(acc[f][r]);
        }
    }
}

// ---------------- standalone gather: 8 lanes/node, uint4 rows, int4 colbuf ----------
// DOV: multiply each gathered row by dov[col] (layer 1's deferred source-side scale)
template <bool DOV>
__global__ __launch_bounds__(256) void gatherH(
    const int* __restrict__ indptr, const int* __restrict__ colbuf,
    const uint4* __restrict__ fin,
    const float* __restrict__ dov,
    const float* __restrict__ di, const float* __restrict__ bias,
    uint4* __restrict__ hout, int ldh, int coff, int N) {
    int j = threadIdx.x & 7;
    int node = blockIdx.x * 32 + (threadIdx.x >> 3);
    if (node >= N) return;
    int beg = indptr[node], end = indptr[node + 1];
    float a[8] = {};
    int e = beg;
    for (; e + 4 <= end; e += 4) {
        int4 cc = *(const int4*)&colbuf[e];
        uint4 u0 = fin[(size_t)cc.x * 8 + j];
        uint4 u1 = fin[(size_t)cc.y * 8 + j];
        uint4 u2 = fin[(size_t)cc.z * 8 + j];
        uint4 u3 = fin[(size_t)cc.w * 8 + j];
        if (DOV) {
            acc8s(u0, a, dov[cc.x]); acc8s(u1, a, dov[cc.y]);
            acc8s(u2, a, dov[cc.z]); acc8s(u3, a, dov[cc.w]);
        } else {
            acc8(u0, a); acc8(u1, a); acc8(u2, a); acc8(u3, a);
        }
    }
    for (; e < end; ++e) {
        int c = colbuf[e];
        uint4 u = fin[(size_t)c * 8 + j];
        if (DOV) acc8s(u, a, dov[c]); else acc8(u, a);
    }
    float dval = di[node];
    float4 b0 = *(const float4*)&bias[j * 8];
    float4 b1 = *(const float4*)&bias[j * 8 + 4];
    float r[8];
    r[0] = fmaxf(a[0] * dval + b0.x, 0.f); r[1] = fmaxf(a[1] * dval + b0.y, 0.f);
    r[2] = fmaxf(a[2] * dval + b0.z, 0.f); r[3] = fmaxf(a[3] * dval + b0.w, 0.f);
    r[4] = fmaxf(a[4] * dval + b1.x, 0.f); r[5] = fmaxf(a[5] * dval + b1.y, 0.f);
    r[6] = fmaxf(a[6] * dval + b1.z, 0.f); r[7] = fmaxf(a[7] * dval + b1.w, 0.f);
    uint4 o;
    o.x = pack2(r[0], r[1]); o.y = pack2(r[2], r[3]);
    o.z = pack2(r[4], r[5]); o.w = pack2(r[6], r[7]);
    hout[(size_t)node * ldh + coff + j] = o;
}

// ---------------- final gather ----------------
__global__ __launch_bounds__(256) void final_gather(
    const int* __restrict__ indptr, const int* __restrict__ colbuf,
    const uint4* __restrict__ P4,
    const float* __restrict__ bm,
    float* __restrict__ out, int N) {
    int j = threadIdx.x & 3;
    int node = blockIdx.x * 64 + (threadIdx.x >> 2);
    if (node >= N) return;
    int beg = indptr[node], end = indptr[node + 1];
    float a[8] = {};
    int e = beg;
    for (; e + 4 <= end; e += 4) {
        int4 cc = *(const int4*)&colbuf[e];
        uint4 u0 = P4[(size_t)cc.x * 4 + j];
        uint4 u1 = P4[(size_t)cc.y * 4 + j];
        uint4 u2 = P4[(size_t)cc.z * 4 + j];
        uint4 u3 = P4[(size_t)cc.w * 4 + j];
        acc8(u0, a); acc8(u1, a); acc8(u2, a); acc8(u3, a);
    }
    for (; e < end; ++e) acc8(P4[(size_t)colbuf[e] * 4 + j], a);
    float4 b0 = *(const float4*)&bm[j * 8];
    float4 b1 = *(const float4*)&bm[j * 8 + 4];
    float4 o0 = make_float4(a[0] + b0.x, a[1] + b0.y, a[2] + b0.z, a[3] + b0.w);
    float4 o1 = make_float4(a[4] + b1.x, a[5] + b1.y, a[6] + b1.z, a[7] + b1.w);
    *(float4*)&out[(size_t)node * 32 + j * 8] = o0;
    *(float4*)&out[(size_t)node * 32 + j * 8 + 4] = o1;
}

// ---------------- launch ----------------
extern "C" void kernel_launch(void* const* d_in, const int* in_sizes, int n_in,
                              void* d_out, int out_size, void* d_ws, size_t ws_size,
                              hipStream_t stream) {
    const float* feat = (const float*)d_in[0];
    const int*   src  = (const int*)d_in[1];
    const int*   dst  = (const int*)d_in[2];
    const float* W1   = (const float*)d_in[3];
    const float* b1   = (const float*)d_in[4];
    const float* W2   = (const float*)d_in[5];
    const float* b2   = (const float*)d_in[6];
    const float* W3   = (const float*)d_in[7];
    const float* b3   = (const float*)d_in[8];
    const float* Wm   = (const float*)d_in[9];
    const float* bm   = (const float*)d_in[10];
    float* out = (float*)d_out;

    const int N = in_sizes[0] / IN_FEATS;   // 100000
    const int E = in_sizes[1];              // 1600000
    const int NBUCK = (N + 1023) >> BSH;    // 98

    char* wsp = (char*)d_ws;
    auto alloc = [&](size_t bytes) {
        void* p = (void*)wsp;
        wsp += ((bytes + 255) / 256) * 256;
        return p;
    };
    int*   indptr   = (int*)alloc((size_t)(N + 1) * 4);
    int*   colbuf   = (int*)alloc((size_t)E * 4);
    int*   bhd      = (int*)alloc((size_t)NBLK2 * NB * 4);
    int*   bhs      = (int*)alloc((size_t)NBLK2 * NB * 4);
    int*   totd     = (int*)alloc(NB * 4);
    int*   tots     = (int*)alloc(NB * 4);
    int*   based    = (int*)alloc((NB + 1) * 4);
    int*   bases    = (int*)alloc((NB + 1) * 4);
    float* do_isqrt = (float*)alloc((size_t)N * 4);
    float* di_isqrt = (float*)alloc((size_t)N * 4);
    unsigned short* W1t = (unsigned short*)alloc(256 * 64 * 2);
    unsigned short* W2t = (unsigned short*)alloc(64 * 64 * 2);
    unsigned short* W3t = (unsigned short*)alloc(64 * 64 * 2);
    unsigned short* Wmt = (unsigned short*)alloc(192 * 32 * 2);
    unsigned short* Hb  = (unsigned short*)alloc((size_t)N * JK * 2);
    int*   pairbuf  = (int*)alloc((size_t)E * 4);
    int*   srctmp   = (int*)alloc((size_t)E * 4);
    unsigned short* tmp = (unsigned short*)alloc((size_t)N * HID * 2);
    unsigned short* P   = (unsigned short*)alloc((size_t)N * OUTF * 2);

    const int GB = (N + 63) / 64;      // 1563
    const int GGB = (N + 31) / 32;     // 3125

    p1_hist<<<NBLK2, 256, 0, stream>>>(src, dst, E, bhd, bhs);
    p2a_tot<<<2 * NB + 120, 256, 0, stream>>>(bhd, bhs, totd, tots, NBLK2,
                                              W1, W2, W3, Wm, W1t, W2t, W3t, Wmt);
    p2b_scan<<<2, NB, 0, stream>>>(totd, tots, based, bases);
    p2c_off<<<2 * NB, 256, 0, stream>>>(bhd, bhs, based, bases, NBLK2);
    // overlapped: edge partition (latency-bound) + unscaled layer-1 GEMM (BW-bound)
    p3m<<<NBLK2 + GB, 256, 0, stream>>>(src, dst, E, bhd, bhs, pairbuf, srctmp,
                                        feat, W1t, tmp, N);
    p4c<<<2 * NBUCK, 256, 0, stream>>>(pairbuf, srctmp, based, bases, indptr, colbuf,
                                       di_isqrt, do_isqrt, N, E, NBUCK);

    // layer 1 gather applies deferred dov scale per edge: (dov.x)@W == dov.(x@W)
    gatherH<true><<<GGB, 256, 0, stream>>>(indptr, colbuf, (const uint4*)tmp, do_isqrt,
                                           di_isqrt, b1, (uint4*)Hb, 24, 0, N);
    mgemm<HID, HID><<<GB, 256, 0, stream>>>(Hb, JK, W2t, do_isqrt, tmp, HID, N);
    gatherH<false><<<GGB, 256, 0, stream>>>(indptr, colbuf, (const uint4*)tmp, nullptr,
                                            di_isqrt, b2, (uint4*)Hb, 24, 8, N);
    mgemm<HID, HID><<<GB, 256, 0, stream>>>(Hb + HID, JK, W3t, do_isqrt, tmp, HID, N);
    gatherH<false><<<GGB, 256, 0, stream>>>(indptr, colbuf, (const uint4*)tmp, nullptr,
                                            di_isqrt, b3, (uint4*)Hb, 24, 16, N);
    mgemm<OUTF, JK><<<GB, 256, 0, stream>>>(Hb, JK, Wmt, nullptr, P, OUTF, N);
    final_gather<<<(N + 63) / 64, 256, 0, stream>>>(indptr, colbuf, (const uint4*)P, bm, out, N);
}